// Round 1
// baseline (664.118 us; speedup 1.0000x reference)
//
#include <hip/hip_runtime.h>
#include <math.h>

#define L 128
#define B 4
#define H 768
#define R 24
#define LB 512     // L*B
#define H4 192     // H/4
#define LN_EPS 1e-5f

// ---------------------------------------------------------------------------
// Kernel A: gpre[m][k] = sum_h hs[m][h]*r_w[k][h] + hr[m][h]*r_w[k][H+h]
// grid 128 blocks (4 rows each), block 256 (each thread 3 k's)
// ---------------------------------------------------------------------------
__global__ __launch_bounds__(256) void kA(const float* __restrict__ h_re,
                                          const float* __restrict__ h_share,
                                          const float* __restrict__ r_w,
                                          float* __restrict__ gpre) {
    __shared__ float4 shs[4][H4];
    __shared__ float4 shr[4][H4];
    int tid = threadIdx.x;
    int m0  = blockIdx.x * 4;
    const float4* hs4 = (const float4*)h_share;
    const float4* hr4 = (const float4*)h_re;
    for (int v = tid; v < 4 * H4; v += 256) {
        int row = v / H4, c = v % H4;
        shs[row][c] = hs4[(m0 + row) * H4 + c];
        shr[row][c] = hr4[(m0 + row) * H4 + c];
    }
    __syncthreads();
    const float4* w4 = (const float4*)r_w;   // row k = 384 float4
    float acc[4][3];
#pragma unroll
    for (int r = 0; r < 4; r++)
#pragma unroll
        for (int kk = 0; kk < 3; kk++) acc[r][kk] = 0.f;
    int k0 = tid;
    for (int h = 0; h < H4; h++) {
        float4 a[4], b_[4];
#pragma unroll
        for (int r = 0; r < 4; r++) { a[r] = shs[r][h]; b_[r] = shr[r][h]; }
#pragma unroll
        for (int kk = 0; kk < 3; kk++) {
            int k = k0 + 256 * kk;
            float4 wsh = w4[k * 384 + h];
            float4 wre = w4[k * 384 + H4 + h];
#pragma unroll
            for (int r = 0; r < 4; r++) {
                acc[r][kk] += a[r].x * wsh.x + a[r].y * wsh.y + a[r].z * wsh.z + a[r].w * wsh.w
                            + b_[r].x * wre.x + b_[r].y * wre.y + b_[r].z * wre.z + b_[r].w * wre.w;
            }
        }
    }
#pragma unroll
    for (int r = 0; r < 4; r++)
#pragma unroll
        for (int kk = 0; kk < 3; kk++)
            gpre[(m0 + r) * H + k0 + 256 * kk] = acc[r][kk];
}

// ---------------------------------------------------------------------------
// Kernel B: p1[m][k] = sum_h hr[m][h]*hid_w[k][h];  p2: cols H..2H-1
// ---------------------------------------------------------------------------
__global__ __launch_bounds__(256) void kB(const float* __restrict__ h_re,
                                          const float* __restrict__ hid_w,
                                          float* __restrict__ p1,
                                          float* __restrict__ p2) {
    __shared__ float4 shr[4][H4];
    int tid = threadIdx.x;
    int m0  = blockIdx.x * 4;
    const float4* hr4 = (const float4*)h_re;
    for (int v = tid; v < 4 * H4; v += 256) {
        int row = v / H4, c = v % H4;
        shr[row][c] = hr4[(m0 + row) * H4 + c];
    }
    __syncthreads();
    const float4* w4 = (const float4*)hid_w;   // row k = 576 float4
    float acc1[4][3], acc2[4][3];
#pragma unroll
    for (int r = 0; r < 4; r++)
#pragma unroll
        for (int kk = 0; kk < 3; kk++) { acc1[r][kk] = 0.f; acc2[r][kk] = 0.f; }
    int k0 = tid;
    for (int h = 0; h < H4; h++) {
        float4 b_[4];
#pragma unroll
        for (int r = 0; r < 4; r++) b_[r] = shr[r][h];
#pragma unroll
        for (int kk = 0; kk < 3; kk++) {
            int k = k0 + 256 * kk;
            float4 w1 = w4[k * 576 + h];
            float4 w2 = w4[k * 576 + H4 + h];
#pragma unroll
            for (int r = 0; r < 4; r++) {
                acc1[r][kk] += b_[r].x * w1.x + b_[r].y * w1.y + b_[r].z * w1.z + b_[r].w * w1.w;
                acc2[r][kk] += b_[r].x * w2.x + b_[r].y * w2.y + b_[r].z * w2.z + b_[r].w * w2.w;
            }
        }
    }
#pragma unroll
    for (int r = 0; r < 4; r++)
#pragma unroll
        for (int kk = 0; kk < 3; kk++) {
            p1[(m0 + r) * H + k0 + 256 * kk] = acc1[r][kk];
            p2[(m0 + r) * H + k0 + 256 * kk] = acc2[r][kk];
        }
}

// ---------------------------------------------------------------------------
// maxg: g[b][k] = tanh(max_l gpre[(l*B+b)][k] + r_b[k])  (tanh monotone)
// ---------------------------------------------------------------------------
__global__ __launch_bounds__(256) void kMaxG(const float* __restrict__ gpre,
                                             const float* __restrict__ r_b,
                                             float* __restrict__ g) {
    int t = blockIdx.x * 256 + threadIdx.x;
    if (t >= B * H) return;
    int b = t / H, k = t % H;
    float m = -1e30f;
    for (int l = 0; l < L; l++) m = fmaxf(m, gpre[(l * B + b) * H + k]);
    g[b * H + k] = tanhf(m + r_b[k]);
}

// ---------------------------------------------------------------------------
// pg[b][k] = sum_h g[b][h]*hid_w[k][2H+h] + hid_b[k]
// grid (3, 4): x = k-tile, y = b
// ---------------------------------------------------------------------------
__global__ __launch_bounds__(256) void kPg(const float* __restrict__ g,
                                           const float* __restrict__ hid_w,
                                           const float* __restrict__ hid_b,
                                           float* __restrict__ pg) {
    __shared__ float4 sg[H4];
    int b = blockIdx.y, tid = threadIdx.x;
    const float4* g4 = (const float4*)(g + b * H);
    for (int v = tid; v < H4; v += 256) sg[v] = g4[v];
    __syncthreads();
    int k = blockIdx.x * 256 + tid;
    const float4* w4 = (const float4*)hid_w;
    float acc = 0.f;
    for (int h = 0; h < H4; h++) {
        float4 gv = sg[h];
        float4 wv = w4[k * 576 + 2 * H4 + h];
        acc += gv.x * wv.x + gv.y * wv.y + gv.z * wv.z + gv.w * wv.w;
    }
    pg[b * H + k] = acc + hid_b[k];
}

// ---------------------------------------------------------------------------
// Kernel C (fused): for block (i, b, jg): 16 j's.
//   z[h] = p1[i,b,h] + p2[j,b,h] + pg[b,h]; LayerNorm over h; ELU;
//   out[i,j,b,r] = sigmoid(zln . rel_w[r] + rel_b[r]) * mask[i,b]*mask[j,b]
// block = 128 threads (2 waves). LDS zln[16][772] = 49408 B.
// ---------------------------------------------------------------------------
__global__ __launch_bounds__(128) void kC(const float* __restrict__ p1,
                                          const float* __restrict__ p2,
                                          const float* __restrict__ pg,
                                          const float* __restrict__ ln_g,
                                          const float* __restrict__ ln_b,
                                          const float* __restrict__ rel_w,
                                          const float* __restrict__ rel_b,
                                          const float* __restrict__ mask,
                                          float* __restrict__ out) {
    __shared__ float zln[16][H + 4];   // +4 pad: keeps 16B align, breaks bank collisions
    int i = blockIdx.x, b = blockIdx.y, jg = blockIdx.z;
    int tid  = threadIdx.x;
    int lane = tid & 63, wave = tid >> 6;

    // per-lane constants for h = lane + 64*s
    float t1[12], gg[12], bb[12];
    const float* p1row = p1 + (i * B + b) * H;
    const float* pgrow = pg + b * H;
#pragma unroll
    for (int s = 0; s < 12; s++) {
        int h = lane + 64 * s;
        t1[s] = p1row[h] + pgrow[h];
        gg[s] = ln_g[h];
        bb[s] = ln_b[h];
    }

    // LN + ELU phase: wave w handles j = w*8 .. w*8+7
    for (int jj = 0; jj < 8; jj++) {
        int j = wave * 8 + jj;
        int jglob = jg * 16 + j;
        const float* p2row = p2 + (jglob * B + b) * H;
        float z[12];
        float s1 = 0.f, s2 = 0.f;
#pragma unroll
        for (int s = 0; s < 12; s++) {
            float v = t1[s] + p2row[lane + 64 * s];
            z[s] = v;
            s1 += v; s2 += v * v;
        }
#pragma unroll
        for (int off = 32; off > 0; off >>= 1) {
            s1 += __shfl_xor(s1, off, 64);
            s2 += __shfl_xor(s2, off, 64);
        }
        float mu  = s1 * (1.f / H);
        float var = s2 * (1.f / H) - mu * mu;
        float rs  = rsqrtf(var + LN_EPS);
#pragma unroll
        for (int s = 0; s < 12; s++) {
            float zn = (z[s] - mu) * rs * gg[s] + bb[s];
            zln[j][lane + 64 * s] = zn > 0.f ? zn : expm1f(zn);
        }
    }
    __syncthreads();

    // rel phase: thread -> (j = tid&15, r = tid>>4 (+8,+16))
    int j = tid & 15, rbase = tid >> 4;
    const float4* z4 = (const float4*)(&zln[j][0]);
    const float4* w4 = (const float4*)rel_w;
    float acc[3] = {0.f, 0.f, 0.f};
    for (int h = 0; h < H4; h++) {
        float4 zv = z4[h];
#pragma unroll
        for (int s = 0; s < 3; s++) {
            float4 wv = w4[(rbase + 8 * s) * H4 + h];
            acc[s] += zv.x * wv.x + zv.y * wv.y + zv.z * wv.z + zv.w * wv.w;
        }
    }
    int jglob = jg * 16 + j;
    float mval = mask[i * B + b] * mask[jglob * B + b];
#pragma unroll
    for (int s = 0; s < 3; s++) {
        int r = rbase + 8 * s;
        float v = 1.f / (1.f + expf(-(acc[s] + rel_b[r])));
        out[((i * L + jglob) * B + b) * R + r] = v * mval;
    }
}

// ---------------------------------------------------------------------------
extern "C" void kernel_launch(void* const* d_in, const int* in_sizes, int n_in,
                              void* d_out, int out_size, void* d_ws, size_t ws_size,
                              hipStream_t stream) {
    const float* h_re    = (const float*)d_in[0];
    const float* h_share = (const float*)d_in[1];
    const float* mask    = (const float*)d_in[2];
    const float* r_w     = (const float*)d_in[3];
    const float* r_b     = (const float*)d_in[4];
    const float* hid_w   = (const float*)d_in[5];
    const float* hid_b   = (const float*)d_in[6];
    const float* ln_g    = (const float*)d_in[7];
    const float* ln_b    = (const float*)d_in[8];
    const float* rel_w   = (const float*)d_in[9];
    const float* rel_b   = (const float*)d_in[10];
    float* out = (float*)d_out;

    float* ws   = (float*)d_ws;
    float* gpre = ws;             // 512*768 = 393216
    float* g    = ws + 393216;    // 3072
    float* p1   = ws + 396288;    // 393216
    float* p2   = ws + 789504;    // 393216
    float* pg   = ws + 1182720;   // 3072   (total ~4.5 MB)

    kA<<<128, 256, 0, stream>>>(h_re, h_share, r_w, gpre);
    kB<<<128, 256, 0, stream>>>(h_re, hid_w, p1, p2);
    kMaxG<<<12, 256, 0, stream>>>(gpre, r_b, g);
    kPg<<<dim3(3, 4), 256, 0, stream>>>(g, hid_w, hid_b, pg);
    kC<<<dim3(L, B, 8), 128, 0, stream>>>(p1, p2, pg, ln_g, ln_b,
                                          rel_w, rel_b, mask, out);
}

// Round 3
// 291.965 us; speedup vs baseline: 2.2746x; 2.2746x over previous
//
#include <hip/hip_runtime.h>
#include <math.h>

#define L 128
#define B 4
#define H 768
#define LN_EPS 1e-5f

// ---------------------------------------------------------------------------
// kAB: both GEMMs in one launch.
//   blocks 0..95   (kA): gpre[m][n] = sum_{k'=0..1535} Acat[m][k'] * r_w[n*1536+k']
//                         Acat[m] = [h_share[m] | h_re[m]]
//   blocks 96..287 (kB): p12[m][n] = sum_{k=0..767} h_re[m][k] * Wb[n][k]
//                         Wb[n][k] = hid_w[(n%768)*2304 + (n/768)*768 + k]
// tile 64x64, 256 threads, 4x4 per thread, K-step 32.
// ---------------------------------------------------------------------------
__global__ __launch_bounds__(256) void kAB(const float* __restrict__ h_re,
                                           const float* __restrict__ h_share,
                                           const float* __restrict__ r_w,
                                           const float* __restrict__ hid_w,
                                           float* __restrict__ gpre,
                                           float* __restrict__ p12) {
    __shared__ float sA[32][68];
    __shared__ float sW[32][68];
    int id = blockIdx.x, tid = threadIdx.x;
    bool isA = id < 96;
    int bm, bn, ksteps, wstride, ldc;
    const float *a0, *a1, *wbase;
    float* cbase;
    if (isA) {
        bm = id & 7; bn = id >> 3;
        a0 = h_share; a1 = h_re; ksteps = 48;
        wbase = r_w + (size_t)(bn * 64) * 1536; wstride = 1536;
        cbase = gpre + bn * 64; ldc = 768;
    } else {
        int id2 = id - 96;
        bm = id2 & 7; bn = id2 >> 3;
        int n0 = bn * 64;
        int half = (n0 >= 768) ? 1 : 0;
        a0 = h_re; a1 = h_re; ksteps = 24;
        wbase = hid_w + (size_t)(n0 - half * 768) * 2304 + half * 768; wstride = 2304;
        cbase = p12 + n0; ldc = 1536;
    }
    int m0 = bm * 64;
    int mm0 = (tid >> 4) * 4, nn0 = (tid & 15) * 4;
    float acc[4][4] = {};

    for (int ks = 0; ks < ksteps; ks++) {
        int k0 = ks * 32;
        const float* Asrc = (k0 < 768 ? a0 : a1);
        int kloc = (k0 < 768) ? k0 : k0 - 768;   // FIX: 768 is not pow2, & 767 was wrong
#pragma unroll
        for (int it = 0; it < 2; it++) {
            int e = tid + it * 256;
            int m = e >> 3, kq = e & 7;
            float4 av = *(const float4*)(Asrc + (size_t)(m0 + m) * 768 + kloc + kq * 4);
            float4 wv = *(const float4*)(wbase + (size_t)m * wstride + k0 + kq * 4);
            sA[kq * 4 + 0][m] = av.x; sA[kq * 4 + 1][m] = av.y;
            sA[kq * 4 + 2][m] = av.z; sA[kq * 4 + 3][m] = av.w;
            sW[kq * 4 + 0][m] = wv.x; sW[kq * 4 + 1][m] = wv.y;
            sW[kq * 4 + 2][m] = wv.z; sW[kq * 4 + 3][m] = wv.w;
        }
        __syncthreads();
#pragma unroll
        for (int kk = 0; kk < 32; kk++) {
            float4 a4 = *(const float4*)&sA[kk][mm0];
            float4 b4 = *(const float4*)&sW[kk][nn0];
            float av[4] = {a4.x, a4.y, a4.z, a4.w};
            float bv[4] = {b4.x, b4.y, b4.z, b4.w};
#pragma unroll
            for (int i2 = 0; i2 < 4; i2++)
#pragma unroll
                for (int j2 = 0; j2 < 4; j2++)
                    acc[i2][j2] += av[i2] * bv[j2];
        }
        __syncthreads();
    }
#pragma unroll
    for (int i2 = 0; i2 < 4; i2++) {
        float4 o = make_float4(acc[i2][0], acc[i2][1], acc[i2][2], acc[i2][3]);
        *(float4*)(cbase + (size_t)(m0 + mm0 + i2) * ldc + nn0) = o;
    }
}

// ---------------------------------------------------------------------------
// maxg: g[b][k] = tanh(max_l gpre[(l*B+b)][k] + r_b[k])   (tanh monotone)
// ---------------------------------------------------------------------------
__global__ __launch_bounds__(256) void kMaxG(const float* __restrict__ gpre,
                                             const float* __restrict__ r_b,
                                             float* __restrict__ g) {
    int t = blockIdx.x * 256 + threadIdx.x;
    if (t >= B * H) return;
    int b = t / H, k = t % H;
    float m = -1e30f;
#pragma unroll 8
    for (int l = 0; l < L; l++) m = fmaxf(m, gpre[(size_t)(l * B + b) * H + k]);
    g[b * H + k] = tanhf(m + r_b[k]);
}

// ---------------------------------------------------------------------------
// pg[b][k] = sum_h g[b][h]*hid_w[k][2H+h] + hid_b[k]
// ---------------------------------------------------------------------------
__global__ __launch_bounds__(256) void kPg(const float* __restrict__ g,
                                           const float* __restrict__ hid_w,
                                           const float* __restrict__ hid_b,
                                           float* __restrict__ pg) {
    __shared__ float4 sg[192];
    int b = blockIdx.y, tid = threadIdx.x;
    const float4* g4 = (const float4*)(g + b * H);
    for (int v = tid; v < 192; v += 256) sg[v] = g4[v];
    __syncthreads();
    int k = blockIdx.x * 256 + tid;
    const float4* w4 = (const float4*)hid_w;
    float acc = 0.f;
    for (int h = 0; h < 192; h++) {
        float4 gv = sg[h];
        float4 wv = w4[(size_t)k * 576 + 384 + h];
        acc += gv.x * wv.x + gv.y * wv.y + gv.z * wv.z + gv.w * wv.w;
    }
    pg[b * H + k] = acc + hid_b[k];
}

// ---------------------------------------------------------------------------
// kC: block (i, b, jg) handles 16 j's. 256 threads (4 waves).
// LN+ELU in fp32 (wave-parallel), zln stored bf16 in LDS (24.8 KB),
// rel projection reads bf16 + fp32 weights.
// ---------------------------------------------------------------------------
__global__ __launch_bounds__(256) void kC(const float* __restrict__ p12,
                                          const float* __restrict__ pg,
                                          const float* __restrict__ ln_g,
                                          const float* __restrict__ ln_b,
                                          const float* __restrict__ rel_w,
                                          const float* __restrict__ rel_b,
                                          const float* __restrict__ mask,
                                          float* __restrict__ out) {
    __shared__ unsigned short zls[16][776];   // 16 rows x 768 bf16 (+8 pad)
    int i = blockIdx.x, b = blockIdx.y, jg = blockIdx.z;
    int tid = threadIdx.x, lane = tid & 63, wave = tid >> 6;

    float t1[12], gg[12], bb[12];
    const float* p1row = p12 + (size_t)(i * B + b) * 1536;
    const float* pgrow = pg + b * H;
#pragma unroll
    for (int s = 0; s < 12; s++) {
        int h = lane + 64 * s;
        t1[s] = p1row[h] + pgrow[h];
        gg[s] = ln_g[h];
        bb[s] = ln_b[h];
    }

#pragma unroll
    for (int jj = 0; jj < 4; jj++) {
        int j = wave * 4 + jj;
        int jglob = jg * 16 + j;
        const float* p2row = p12 + (size_t)(jglob * B + b) * 1536 + 768;
        float z[12];
        float s1 = 0.f, s2 = 0.f;
#pragma unroll
        for (int s = 0; s < 12; s++) {
            float v = t1[s] + p2row[lane + 64 * s];
            z[s] = v; s1 += v; s2 += v * v;
        }
#pragma unroll
        for (int off = 32; off > 0; off >>= 1) {
            s1 += __shfl_xor(s1, off, 64);
            s2 += __shfl_xor(s2, off, 64);
        }
        float mu  = s1 * (1.f / H);
        float var = s2 * (1.f / H) - mu * mu;
        float rs  = rsqrtf(var + LN_EPS);
#pragma unroll
        for (int s = 0; s < 12; s++) {
            float zn = (z[s] - mu) * rs * gg[s] + bb[s];
            zn = zn > 0.f ? zn : expm1f(zn);
            unsigned int ub = __float_as_uint(zn);
            zls[j][lane + 64 * s] =
                (unsigned short)((ub + 0x7FFFu + ((ub >> 16) & 1u)) >> 16);
        }
    }
    __syncthreads();

    int j = tid & 15, rb = tid >> 4;
    int jglob = jg * 16 + j;
    const uint4* zr = (const uint4*)&zls[j][0];
    const float4* w4 = (const float4*)rel_w;
    float mval = mask[i * B + b] * mask[jglob * B + b];
    size_t obase = ((size_t)(i * L + jglob) * B + b) * 24;

    if (rb < 8) {                       // waves 0,1: two r's each
        const float4* wr0 = w4 + rb * 192;
        const float4* wr1 = w4 + (rb + 16) * 192;
        float acc0 = 0.f, acc1 = 0.f;
#pragma unroll 2
        for (int c = 0; c < 96; c++) {
            uint4 uv = zr[c];
            float f0 = __uint_as_float(uv.x << 16);
            float f1 = __uint_as_float(uv.x & 0xffff0000u);
            float f2 = __uint_as_float(uv.y << 16);
            float f3 = __uint_as_float(uv.y & 0xffff0000u);
            float f4 = __uint_as_float(uv.z << 16);
            float f5 = __uint_as_float(uv.z & 0xffff0000u);
            float f6 = __uint_as_float(uv.w << 16);
            float f7 = __uint_as_float(uv.w & 0xffff0000u);
            float4 wa = wr0[2 * c], wb = wr0[2 * c + 1];
            acc0 += f0 * wa.x + f1 * wa.y + f2 * wa.z + f3 * wa.w
                  + f4 * wb.x + f5 * wb.y + f6 * wb.z + f7 * wb.w;
            wa = wr1[2 * c]; wb = wr1[2 * c + 1];
            acc1 += f0 * wa.x + f1 * wa.y + f2 * wa.z + f3 * wa.w
                  + f4 * wb.x + f5 * wb.y + f6 * wb.z + f7 * wb.w;
        }
        float v0 = 1.f / (1.f + expf(-(acc0 + rel_b[rb])));
        out[obase + rb] = v0 * mval;
        float v1 = 1.f / (1.f + expf(-(acc1 + rel_b[rb + 16])));
        out[obase + rb + 16] = v1 * mval;
    } else {                            // waves 2,3: one r each
        const float4* wr0 = w4 + rb * 192;
        float acc0 = 0.f;
#pragma unroll 2
        for (int c = 0; c < 96; c++) {
            uint4 uv = zr[c];
            float f0 = __uint_as_float(uv.x << 16);
            float f1 = __uint_as_float(uv.x & 0xffff0000u);
            float f2 = __uint_as_float(uv.y << 16);
            float f3 = __uint_as_float(uv.y & 0xffff0000u);
            float f4 = __uint_as_float(uv.z << 16);
            float f5 = __uint_as_float(uv.z & 0xffff0000u);
            float f6 = __uint_as_float(uv.w << 16);
            float f7 = __uint_as_float(uv.w & 0xffff0000u);
            float4 wa = wr0[2 * c], wb = wr0[2 * c + 1];
            acc0 += f0 * wa.x + f1 * wa.y + f2 * wa.z + f3 * wa.w
                  + f4 * wb.x + f5 * wb.y + f6 * wb.z + f7 * wb.w;
        }
        float v0 = 1.f / (1.f + expf(-(acc0 + rel_b[rb])));
        out[obase + rb] = v0 * mval;
    }
}

// ---------------------------------------------------------------------------
extern "C" void kernel_launch(void* const* d_in, const int* in_sizes, int n_in,
                              void* d_out, int out_size, void* d_ws, size_t ws_size,
                              hipStream_t stream) {
    const float* h_re    = (const float*)d_in[0];
    const float* h_share = (const float*)d_in[1];
    const float* mask    = (const float*)d_in[2];
    const float* r_w     = (const float*)d_in[3];
    const float* r_b     = (const float*)d_in[4];
    const float* hid_w   = (const float*)d_in[5];
    const float* hid_b   = (const float*)d_in[6];
    const float* ln_g    = (const float*)d_in[7];
    const float* ln_b    = (const float*)d_in[8];
    const float* rel_w   = (const float*)d_in[9];
    const float* rel_b   = (const float*)d_in[10];
    float* out = (float*)d_out;

    float* ws   = (float*)d_ws;
    float* gpre = ws;               // 512*768  = 393216
    float* p12  = ws + 393216;      // 512*1536 = 786432
    float* g    = ws + 1179648;     // 3072
    float* pg   = ws + 1182720;     // 3072

    kAB<<<288, 256, 0, stream>>>(h_re, h_share, r_w, hid_w, gpre, p12);
    kMaxG<<<12, 256, 0, stream>>>(gpre, r_b, g);
    kPg<<<dim3(3, 4), 256, 0, stream>>>(g, hid_w, hid_b, pg);
    kC<<<dim3(L, B, 8), 256, 0, stream>>>(p12, pg, ln_g, ln_b,
                                          rel_w, rel_b, mask, out);
}

// Round 4
// 127.475 us; speedup vs baseline: 5.2098x; 2.2904x over previous
//
#include <hip/hip_runtime.h>
#include <math.h>

#define L 128
#define B 4
#define H 768
#define LN_EPS 1e-5f

typedef __attribute__((ext_vector_type(8))) short short8;
typedef __attribute__((ext_vector_type(4))) float f32x4;

static __device__ __forceinline__ unsigned f2bfu(float f) {
    unsigned u = __float_as_uint(f);
    return (u + 0x7FFFu + ((u >> 16) & 1u)) >> 16;
}
static __device__ __forceinline__ short8 pack8(const float* v) {
    short8 s;
#pragma unroll
    for (int e = 0; e < 8; e++) s[e] = (short)f2bfu(v[e]);
    return s;
}

// ---------------------------------------------------------------------------
// kAB: both GEMMs via bf16 MFMA. C[m][n] = sum_k Acat[m][k] * W[n][k].
//   blocks 0..191  (A): M=512,N=768,K=1536; Acat=[h_share|h_re]; W=r_w; C=gpre
//   blocks 192..575(B): M=512,N=1536,K=768; A=h_re; W[n][k]=hid_w[(n%768)*2304+(n/768)*768+k]; C=p12
// BM=32, BN=64, 256 thr (4 waves). wave w: Ntile w, Mtiles 0..1. K-chunk 64 in LDS.
// ---------------------------------------------------------------------------
__global__ __launch_bounds__(256) void kAB(const float* __restrict__ h_re,
                                           const float* __restrict__ h_share,
                                           const float* __restrict__ r_w,
                                           const float* __restrict__ hid_w,
                                           float* __restrict__ gpre,
                                           float* __restrict__ p12) {
    __shared__ short sA[32][72];   // 32 m-rows x 64 k (bf16), row padded to 72
    __shared__ short sW[64][72];   // 64 n-rows x 64 k (bf16)
    int id = blockIdx.x, tid = threadIdx.x;
    int lane = tid & 63, wave = tid >> 6;
    int lq = lane >> 4, lr = lane & 15;

    bool isA = id < 192;
    int bm, n0, nchunks, wstride, ldc;
    const float *wbase;
    float* cbase;
    if (isA) {
        bm = id & 15; n0 = (id >> 4) * 64;
        wbase = r_w + (size_t)n0 * 1536; wstride = 1536;
        cbase = gpre + n0; ldc = 768; nchunks = 24;
    } else {
        int id2 = id - 192;
        bm = id2 & 15; n0 = (id2 >> 4) * 64;
        int half = (n0 >= 768) ? 1 : 0;
        wbase = hid_w + (size_t)(n0 - half * 768) * 2304 + half * 768;
        wstride = 2304;
        cbase = p12 + n0; ldc = 1536; nchunks = 12;
    }
    int m0 = bm * 32;

    f32x4 acc0 = {0.f, 0.f, 0.f, 0.f}, acc1 = {0.f, 0.f, 0.f, 0.f};
    int srow = tid >> 3, sk8 = tid & 7;

    for (int c = 0; c < nchunks; c++) {
        int kc = c * 64;
        __syncthreads();
        // stage A chunk (1 row-piece per thread)
        {
            const float* src;
            if (isA && kc >= 768)
                src = h_re + (size_t)(m0 + srow) * 768 + (kc - 768) + sk8 * 8;
            else
                src = (isA ? h_share : h_re) + (size_t)(m0 + srow) * 768 + kc + sk8 * 8;
            float4 x = *(const float4*)src;
            float4 y = *(const float4*)(src + 4);
            float tmp[8] = {x.x, x.y, x.z, x.w, y.x, y.y, y.z, y.w};
            *(short8*)&sA[srow][sk8 * 8] = pack8(tmp);
        }
        // stage W chunk (2 row-pieces per thread)
#pragma unroll
        for (int it = 0; it < 2; it++) {
            int wr = srow + it * 32;
            const float* wsrc = wbase + (size_t)wr * wstride + kc + sk8 * 8;
            float4 u = *(const float4*)wsrc;
            float4 v = *(const float4*)(wsrc + 4);
            float tmp[8] = {u.x, u.y, u.z, u.w, v.x, v.y, v.z, v.w};
            *(short8*)&sW[wr][sk8 * 8] = pack8(tmp);
        }
        __syncthreads();
#pragma unroll
        for (int kl = 0; kl < 2; kl++) {
            int ko = kl * 32 + lq * 8;
            short8 bf = *(const short8*)&sW[wave * 16 + lr][ko];
            short8 a0 = *(const short8*)&sA[lr][ko];
            short8 a1 = *(const short8*)&sA[16 + lr][ko];
            acc0 = __builtin_amdgcn_mfma_f32_16x16x32_bf16(a0, bf, acc0, 0, 0, 0);
            acc1 = __builtin_amdgcn_mfma_f32_16x16x32_bf16(a1, bf, acc1, 0, 0, 0);
        }
    }
#pragma unroll
    for (int q = 0; q < 4; q++) {
        int r0 = m0 + lq * 4 + q;
        cbase[(size_t)r0 * ldc + wave * 16 + lr] = acc0[q];
        cbase[(size_t)(r0 + 16) * ldc + wave * 16 + lr] = acc1[q];
    }
}

// ---------------------------------------------------------------------------
// kMaxG: g[b][k] = tanh(max_l gpre[(l*B+b)][k] + r_b[k]). grid (12,4), 256 thr.
// ---------------------------------------------------------------------------
__global__ __launch_bounds__(256) void kMaxG(const float* __restrict__ gpre,
                                             const float* __restrict__ r_b,
                                             float* __restrict__ g) {
    __shared__ float sm[4][64];
    int kt = blockIdx.x, b = blockIdx.y, tid = threadIdx.x;
    int kk = tid & 63, lc = tid >> 6;
    int k = kt * 64 + kk;
    float m = -1e30f;
#pragma unroll 4
    for (int l = lc * 32; l < lc * 32 + 32; l++)
        m = fmaxf(m, gpre[(size_t)(l * 4 + b) * 768 + k]);
    sm[lc][kk] = m;
    __syncthreads();
    if (lc == 0) {
        m = fmaxf(fmaxf(sm[0][kk], sm[1][kk]), fmaxf(sm[2][kk], sm[3][kk]));
        g[b * 768 + k] = tanhf(m + r_b[k]);
    }
}

// ---------------------------------------------------------------------------
// kPg: pg[b][k] = sum_h g[b][h]*hid_w[k][1536+h] + hid_b[k]. grid (12,4).
// ---------------------------------------------------------------------------
__global__ __launch_bounds__(256) void kPg(const float* __restrict__ g,
                                           const float* __restrict__ hid_w,
                                           const float* __restrict__ hid_b,
                                           float* __restrict__ pg) {
    __shared__ float4 sg[192];
    __shared__ float sp[4][64];
    int kt = blockIdx.x, b = blockIdx.y, tid = threadIdx.x;
    int kk = tid & 63, hc = tid >> 6;
    int k = kt * 64 + kk;
    const float4* g4 = (const float4*)(g + b * 768);
    for (int v = tid; v < 192; v += 256) sg[v] = g4[v];
    __syncthreads();
    const float4* w4 = (const float4*)hid_w;
    float acc = 0.f;
    for (int h = hc * 48; h < hc * 48 + 48; h++) {
        float4 gv = sg[h];
        float4 wv = w4[(size_t)k * 576 + 384 + h];
        acc += gv.x * wv.x + gv.y * wv.y + gv.z * wv.z + gv.w * wv.w;
    }
    sp[hc][kk] = acc;
    __syncthreads();
    if (hc == 0)
        pg[b * 768 + k] = sp[0][kk] + sp[1][kk] + sp[2][kk] + sp[3][kk] + hid_b[k];
}

// ---------------------------------------------------------------------------
// kC: block (i, b, jg) handles 32 j's. 256 thr (4 waves).
// Phase 1: LN+ELU -> zls bf16 [32][776]. Phase 2: rel projection via MFMA:
// wave w -> Mtile=w&1 (16 j's), Ntile=w>>1 (16 r's, tile1 has 8 valid).
// ---------------------------------------------------------------------------
__global__ __launch_bounds__(256) void kC(const float* __restrict__ p12,
                                          const float* __restrict__ pg,
                                          const float* __restrict__ ln_g,
                                          const float* __restrict__ ln_b,
                                          const float* __restrict__ rel_w,
                                          const float* __restrict__ rel_b,
                                          const float* __restrict__ mask,
                                          float* __restrict__ out) {
    __shared__ unsigned short zls[32][776];
    int i = blockIdx.x, b = blockIdx.y, j0 = blockIdx.z * 32;
    int tid = threadIdx.x, lane = tid & 63, wave = tid >> 6;

    const float4* p1r = (const float4*)(p12 + (size_t)(i * 4 + b) * 1536);
    const float4* pg4 = (const float4*)(pg + b * 768);
    const float4* lg4 = (const float4*)ln_g;
    const float4* lb4 = (const float4*)ln_b;
    float4 t1[3], gg[3], bb[3];
#pragma unroll
    for (int s = 0; s < 3; s++) {
        int c = lane + 64 * s;
        float4 x = p1r[c], y = pg4[c];
        t1[s] = make_float4(x.x + y.x, x.y + y.y, x.z + y.z, x.w + y.w);
        gg[s] = lg4[c];
        bb[s] = lb4[c];
    }

    for (int jj = 0; jj < 8; jj++) {
        int j = wave * 8 + jj;
        int jglob = j0 + j;
        const float4* p2r = (const float4*)(p12 + (size_t)(jglob * 4 + b) * 1536 + 768);
        float4 z[3];
        float s1 = 0.f, s2 = 0.f;
#pragma unroll
        for (int s = 0; s < 3; s++) {
            float4 v = p2r[lane + 64 * s];
            v.x += t1[s].x; v.y += t1[s].y; v.z += t1[s].z; v.w += t1[s].w;
            z[s] = v;
            s1 += v.x + v.y + v.z + v.w;
            s2 += v.x * v.x + v.y * v.y + v.z * v.z + v.w * v.w;
        }
#pragma unroll
        for (int off = 32; off > 0; off >>= 1) {
            s1 += __shfl_xor(s1, off, 64);
            s2 += __shfl_xor(s2, off, 64);
        }
        float mu  = s1 * (1.f / H);
        float var = s2 * (1.f / H) - mu * mu;
        float rs  = rsqrtf(var + LN_EPS);
#pragma unroll
        for (int s = 0; s < 3; s++) {
            float zn0 = (z[s].x - mu) * rs * gg[s].x + bb[s].x;
            float zn1 = (z[s].y - mu) * rs * gg[s].y + bb[s].y;
            float zn2 = (z[s].z - mu) * rs * gg[s].z + bb[s].z;
            float zn3 = (z[s].w - mu) * rs * gg[s].w + bb[s].w;
            zn0 = zn0 > 0.f ? zn0 : expm1f(zn0);
            zn1 = zn1 > 0.f ? zn1 : expm1f(zn1);
            zn2 = zn2 > 0.f ? zn2 : expm1f(zn2);
            zn3 = zn3 > 0.f ? zn3 : expm1f(zn3);
            uint2 u;
            u.x = f2bfu(zn0) | (f2bfu(zn1) << 16);
            u.y = f2bfu(zn2) | (f2bfu(zn3) << 16);
            *(uint2*)&zls[j][lane * 4 + 256 * s] = u;
        }
    }
    __syncthreads();

    // MFMA rel projection
    int lq = lane >> 4, lr = lane & 15;
    int mt = wave & 1, nt = wave >> 1;
    int arow = mt * 16 + lr;
    int r = nt * 16 + lr;
    bool rvalid = r < 24;
    const float* rwrow = rel_w + (size_t)(rvalid ? r : 0) * 768;
    f32x4 acc = {0.f, 0.f, 0.f, 0.f};
#pragma unroll 4
    for (int step = 0; step < 24; step++) {
        int k0 = step * 32 + lq * 8;
        short8 a = *(const short8*)&zls[arow][k0];
        short8 bf = {0, 0, 0, 0, 0, 0, 0, 0};
        if (rvalid) {
            float4 w0 = *(const float4*)(rwrow + k0);
            float4 w1 = *(const float4*)(rwrow + k0 + 4);
            float tmp[8] = {w0.x, w0.y, w0.z, w0.w, w1.x, w1.y, w1.z, w1.w};
            bf = pack8(tmp);
        }
        acc = __builtin_amdgcn_mfma_f32_16x16x32_bf16(a, bf, acc, 0, 0, 0);
    }

    if (rvalid) {
        float rb = rel_b[r];
        float mi = mask[i * 4 + b];
#pragma unroll
        for (int q = 0; q < 4; q++) {
            int jloc = mt * 16 + lq * 4 + q;
            int jglob = j0 + jloc;
            float v = 1.f / (1.f + expf(-(acc[q] + rb)));
            v *= mi * mask[jglob * 4 + b];
            out[((size_t)(i * 128 + jglob) * 4 + b) * 24 + r] = v;
        }
    }
}

// ---------------------------------------------------------------------------
extern "C" void kernel_launch(void* const* d_in, const int* in_sizes, int n_in,
                              void* d_out, int out_size, void* d_ws, size_t ws_size,
                              hipStream_t stream) {
    const float* h_re    = (const float*)d_in[0];
    const float* h_share = (const float*)d_in[1];
    const float* mask    = (const float*)d_in[2];
    const float* r_w     = (const float*)d_in[3];
    const float* r_b     = (const float*)d_in[4];
    const float* hid_w   = (const float*)d_in[5];
    const float* hid_b   = (const float*)d_in[6];
    const float* ln_g    = (const float*)d_in[7];
    const float* ln_b    = (const float*)d_in[8];
    const float* rel_w   = (const float*)d_in[9];
    const float* rel_b   = (const float*)d_in[10];
    float* out = (float*)d_out;

    float* ws   = (float*)d_ws;
    float* gpre = ws;               // 512*768  = 393216
    float* p12  = ws + 393216;      // 512*1536 = 786432
    float* g    = ws + 1179648;     // 3072
    float* pg   = ws + 1182720;     // 3072

    kAB<<<576, 256, 0, stream>>>(h_re, h_share, r_w, hid_w, gpre, p12);
    kMaxG<<<dim3(12, 4), 256, 0, stream>>>(gpre, r_b, g);
    kPg<<<dim3(12, 4), 256, 0, stream>>>(g, hid_w, hid_b, pg);
    kC<<<dim3(L, B, 4), 256, 0, stream>>>(p12, pg, ln_g, ln_b,
                                          rel_w, rel_b, mask, out);
}

// Round 5
// 120.968 us; speedup vs baseline: 5.4900x; 1.0538x over previous
//
#include <hip/hip_runtime.h>
#include <math.h>

#define L 128
#define B 4
#define H 768
#define LN_EPS 1e-5f

typedef __attribute__((ext_vector_type(8))) short short8;
typedef __attribute__((ext_vector_type(4))) float f32x4;

static __device__ __forceinline__ unsigned f2bfu(float f) {
    unsigned u = __float_as_uint(f);
    return (u + 0x7FFFu + ((u >> 16) & 1u)) >> 16;
}
static __device__ __forceinline__ short8 pack8(const float* v) {
    short8 s;
#pragma unroll
    for (int e = 0; e < 8; e++) s[e] = (short)f2bfu(v[e]);
    return s;
}

// ---------------------------------------------------------------------------
// kPrep: rel_w (24x768 f32) -> bf16, zero-padded to 32 rows. grid 96x256.
// ---------------------------------------------------------------------------
__global__ __launch_bounds__(256) void kPrep(const float* __restrict__ rel_w,
                                             unsigned short* __restrict__ rwb) {
    int idx = blockIdx.x * 256 + threadIdx.x;   // 0..24575
    rwb[idx] = (idx < 18432) ? (unsigned short)f2bfu(rel_w[idx]) : (unsigned short)0;
}

// ---------------------------------------------------------------------------
// kAB (unchanged from r4): both GEMMs via bf16 MFMA.
// ---------------------------------------------------------------------------
__global__ __launch_bounds__(256) void kAB(const float* __restrict__ h_re,
                                           const float* __restrict__ h_share,
                                           const float* __restrict__ r_w,
                                           const float* __restrict__ hid_w,
                                           float* __restrict__ gpre,
                                           float* __restrict__ p12) {
    __shared__ short sA[32][72];
    __shared__ short sW[64][72];
    int id = blockIdx.x, tid = threadIdx.x;
    int lane = tid & 63, wave = tid >> 6;
    int lq = lane >> 4, lr = lane & 15;

    bool isA = id < 192;
    int bm, n0, nchunks, wstride, ldc;
    const float *wbase;
    float* cbase;
    if (isA) {
        bm = id & 15; n0 = (id >> 4) * 64;
        wbase = r_w + (size_t)n0 * 1536; wstride = 1536;
        cbase = gpre + n0; ldc = 768; nchunks = 24;
    } else {
        int id2 = id - 192;
        bm = id2 & 15; n0 = (id2 >> 4) * 64;
        int half = (n0 >= 768) ? 1 : 0;
        wbase = hid_w + (size_t)(n0 - half * 768) * 2304 + half * 768;
        wstride = 2304;
        cbase = p12 + n0; ldc = 1536; nchunks = 12;
    }
    int m0 = bm * 32;

    f32x4 acc0 = {0.f, 0.f, 0.f, 0.f}, acc1 = {0.f, 0.f, 0.f, 0.f};
    int srow = tid >> 3, sk8 = tid & 7;

    for (int c = 0; c < nchunks; c++) {
        int kc = c * 64;
        __syncthreads();
        {
            const float* src;
            if (isA && kc >= 768)
                src = h_re + (size_t)(m0 + srow) * 768 + (kc - 768) + sk8 * 8;
            else
                src = (isA ? h_share : h_re) + (size_t)(m0 + srow) * 768 + kc + sk8 * 8;
            float4 x = *(const float4*)src;
            float4 y = *(const float4*)(src + 4);
            float tmp[8] = {x.x, x.y, x.z, x.w, y.x, y.y, y.z, y.w};
            *(short8*)&sA[srow][sk8 * 8] = pack8(tmp);
        }
#pragma unroll
        for (int it = 0; it < 2; it++) {
            int wr = srow + it * 32;
            const float* wsrc = wbase + (size_t)wr * wstride + kc + sk8 * 8;
            float4 u = *(const float4*)wsrc;
            float4 v = *(const float4*)(wsrc + 4);
            float tmp[8] = {u.x, u.y, u.z, u.w, v.x, v.y, v.z, v.w};
            *(short8*)&sW[wr][sk8 * 8] = pack8(tmp);
        }
        __syncthreads();
#pragma unroll
        for (int kl = 0; kl < 2; kl++) {
            int ko = kl * 32 + lq * 8;
            short8 bf = *(const short8*)&sW[wave * 16 + lr][ko];
            short8 a0 = *(const short8*)&sA[lr][ko];
            short8 a1 = *(const short8*)&sA[16 + lr][ko];
            acc0 = __builtin_amdgcn_mfma_f32_16x16x32_bf16(a0, bf, acc0, 0, 0, 0);
            acc1 = __builtin_amdgcn_mfma_f32_16x16x32_bf16(a1, bf, acc1, 0, 0, 0);
        }
    }
#pragma unroll
    for (int q = 0; q < 4; q++) {
        int r0 = m0 + lq * 4 + q;
        cbase[(size_t)r0 * ldc + wave * 16 + lr] = acc0[q];
        cbase[(size_t)(r0 + 16) * ldc + wave * 16 + lr] = acc1[q];
    }
}

// ---------------------------------------------------------------------------
// kMaxG (unchanged)
// ---------------------------------------------------------------------------
__global__ __launch_bounds__(256) void kMaxG(const float* __restrict__ gpre,
                                             const float* __restrict__ r_b,
                                             float* __restrict__ g) {
    __shared__ float sm[4][64];
    int kt = blockIdx.x, b = blockIdx.y, tid = threadIdx.x;
    int kk = tid & 63, lc = tid >> 6;
    int k = kt * 64 + kk;
    float m = -1e30f;
#pragma unroll 4
    for (int l = lc * 32; l < lc * 32 + 32; l++)
        m = fmaxf(m, gpre[(size_t)(l * 4 + b) * 768 + k]);
    sm[lc][kk] = m;
    __syncthreads();
    if (lc == 0) {
        m = fmaxf(fmaxf(sm[0][kk], sm[1][kk]), fmaxf(sm[2][kk], sm[3][kk]));
        g[b * 768 + k] = tanhf(m + r_b[k]);
    }
}

// ---------------------------------------------------------------------------
// kPg (unchanged)
// ---------------------------------------------------------------------------
__global__ __launch_bounds__(256) void kPg(const float* __restrict__ g,
                                           const float* __restrict__ hid_w,
                                           const float* __restrict__ hid_b,
                                           float* __restrict__ pg) {
    __shared__ float4 sg[192];
    __shared__ float sp[4][64];
    int kt = blockIdx.x, b = blockIdx.y, tid = threadIdx.x;
    int kk = tid & 63, hc = tid >> 6;
    int k = kt * 64 + kk;
    const float4* g4 = (const float4*)(g + b * 768);
    for (int v = tid; v < 192; v += 256) sg[v] = g4[v];
    __syncthreads();
    const float4* w4 = (const float4*)hid_w;
    float acc = 0.f;
    for (int h = hc * 48; h < hc * 48 + 48; h++) {
        float4 gv = sg[h];
        float4 wv = w4[(size_t)k * 576 + 384 + h];
        acc += gv.x * wv.x + gv.y * wv.y + gv.z * wv.z + gv.w * wv.w;
    }
    sp[hc][kk] = acc;
    __syncthreads();
    if (hc == 0)
        pg[b * 768 + k] = sp[0][kk] + sp[1][kk] + sp[2][kk] + sp[3][kk] + hid_b[k];
}

// ---------------------------------------------------------------------------
// kStats: per-row sum & sum-of-squares.
//   rows 0..511:  u = p1+pg  -> su1, su2   (row m = i*4+b)
//   rows 512..1023: v = p2   -> sv1, sv2
// grid 256 blocks x 256 thr (1 wave per row).
// ---------------------------------------------------------------------------
__global__ __launch_bounds__(256) void kStats(const float* __restrict__ p12,
                                              const float* __restrict__ pg,
                                              float* __restrict__ su1,
                                              float* __restrict__ su2,
                                              float* __restrict__ sv1,
                                              float* __restrict__ sv2) {
    int row = blockIdx.x * 4 + (threadIdx.x >> 6);
    int lane = threadIdx.x & 63;
    bool isU = row < 512;
    int m = isU ? row : row - 512;
    const float4* src = (const float4*)(p12 + (size_t)m * 1536 + (isU ? 0 : 768));
    const float4* pg4 = (const float4*)(pg + (m & 3) * 768);
    float s1 = 0.f, s2 = 0.f;
#pragma unroll
    for (int s = 0; s < 3; s++) {
        int c = lane + 64 * s;
        float4 v = src[c];
        if (isU) {
            float4 p = pg4[c];
            v.x += p.x; v.y += p.y; v.z += p.z; v.w += p.w;
        }
        s1 += v.x + v.y + v.z + v.w;
        s2 += v.x * v.x + v.y * v.y + v.z * v.z + v.w * v.w;
    }
#pragma unroll
    for (int off = 32; off > 0; off >>= 1) {
        s1 += __shfl_xor(s1, off, 64);
        s2 += __shfl_xor(s2, off, 64);
    }
    if (lane == 0) {
        if (isU) { su1[m] = s1; su2[m] = s2; }
        else     { sv1[m] = s1; sv2[m] = s2; }
    }
}

// ---------------------------------------------------------------------------
// kDot: D[b][i][j] = dot_h(u[i,b,:], v[j,b,:]) in fp32.
// grid (4 it, 8 jt, 4 b), 256 thr. Tile 32i x 16j, K-chunk 64 in LDS.
// ---------------------------------------------------------------------------
__global__ __launch_bounds__(256) void kDot(const float* __restrict__ p12,
                                            const float* __restrict__ pg,
                                            float* __restrict__ D) {
    __shared__ float sU[32][68];
    __shared__ float sV[16][68];
    int i0 = blockIdx.x * 32, j0 = blockIdx.y * 16, b = blockIdx.z;
    int tid = threadIdx.x;
    int urow = tid >> 3, ukq = tid & 7;      // u stage: 2 float4
    int vrow = tid >> 4, vkq = tid & 15;     // v stage: 1 float4
    int ii0 = (tid >> 4) * 2, jj = tid & 15; // compute: 2x1 micro-tile
    float acc0 = 0.f, acc1 = 0.f;

    for (int c = 0; c < 12; c++) {
        int kc = c * 64;
        __syncthreads();
        {
            const float* us = p12 + (size_t)((i0 + urow) * 4 + b) * 1536 + kc + ukq * 8;
            const float* ps = pg + b * 768 + kc + ukq * 8;
            float4 x = *(const float4*)us, y = *(const float4*)ps;
            *(float4*)&sU[urow][ukq * 8] =
                make_float4(x.x + y.x, x.y + y.y, x.z + y.z, x.w + y.w);
            x = *(const float4*)(us + 4); y = *(const float4*)(ps + 4);
            *(float4*)&sU[urow][ukq * 8 + 4] =
                make_float4(x.x + y.x, x.y + y.y, x.z + y.z, x.w + y.w);
            const float* vs = p12 + (size_t)((j0 + vrow) * 4 + b) * 1536 + 768 + kc + vkq * 4;
            *(float4*)&sV[vrow][vkq * 4] = *(const float4*)vs;
        }
        __syncthreads();
#pragma unroll 8
        for (int k = 0; k < 64; k++) {
            float bv = sV[jj][k];
            acc0 += sU[ii0][k] * bv;
            acc1 += sU[ii0 + 1][k] * bv;
        }
    }
    D[b * 16384 + (i0 + ii0) * 128 + (j0 + jj)] = acc0;
    D[b * 16384 + (i0 + ii0 + 1) * 128 + (j0 + jj)] = acc1;
}

// ---------------------------------------------------------------------------
// kC: block (i, b, jg) handles 16 j's. 256 thr (4 waves), LDS 24.9KB -> 6 blk/CU.
// Stats precomputed (no reductions). Phase2: MFMA, K split across wave pairs.
// ---------------------------------------------------------------------------
__global__ __launch_bounds__(256, 6) void kC(const float* __restrict__ p12,
                                             const float* __restrict__ pg,
                                             const float* __restrict__ ln_g,
                                             const float* __restrict__ ln_b,
                                             const unsigned short* __restrict__ rwb,
                                             const float* __restrict__ rel_b,
                                             const float* __restrict__ su1,
                                             const float* __restrict__ su2,
                                             const float* __restrict__ sv1,
                                             const float* __restrict__ sv2,
                                             const float* __restrict__ D,
                                             const float* __restrict__ mask,
                                             float* __restrict__ out) {
    __shared__ unsigned short zls[16][776];
    __shared__ float smu[16], srs[16];
    int i = blockIdx.x, b = blockIdx.y, j0 = blockIdx.z * 16;
    int tid = threadIdx.x, lane = tid & 63, wave = tid >> 6;

    if (tid < 16) {
        int jg = j0 + tid;
        float mu = (su1[i * 4 + b] + sv1[jg * 4 + b]) * (1.f / 768.f);
        float ms = (su2[i * 4 + b] + 2.f * D[b * 16384 + i * 128 + jg] + sv2[jg * 4 + b])
                   * (1.f / 768.f);
        smu[tid] = mu;
        srs[tid] = rsqrtf(ms - mu * mu + LN_EPS);
    }

    const float4* p1r = (const float4*)(p12 + (size_t)(i * 4 + b) * 1536);
    const float4* pg4 = (const float4*)(pg + b * 768);
    const float4* lg4 = (const float4*)ln_g;
    const float4* lb4 = (const float4*)ln_b;
    float4 t1[3], gg[3], bb[3];
#pragma unroll
    for (int s = 0; s < 3; s++) {
        int c = lane + 64 * s;
        float4 x = p1r[c], y = pg4[c];
        t1[s] = make_float4(x.x + y.x, x.y + y.y, x.z + y.z, x.w + y.w);
        gg[s] = lg4[c];
        bb[s] = lb4[c];
    }
    __syncthreads();

    // phase 1: LN+ELU, no reductions. wave handles 4 rows.
#pragma unroll
    for (int jj = 0; jj < 4; jj++) {
        int j = wave * 4 + jj;
        float mu = smu[j], rs = srs[j];
        const float4* p2r = (const float4*)(p12 + (size_t)((j0 + j) * 4 + b) * 1536 + 768);
#pragma unroll
        for (int s = 0; s < 3; s++) {
            float4 v = p2r[lane + 64 * s];
            float zn0 = ((t1[s].x + v.x) - mu) * rs * gg[s].x + bb[s].x;
            float zn1 = ((t1[s].y + v.y) - mu) * rs * gg[s].y + bb[s].y;
            float zn2 = ((t1[s].z + v.z) - mu) * rs * gg[s].z + bb[s].z;
            float zn3 = ((t1[s].w + v.w) - mu) * rs * gg[s].w + bb[s].w;
            zn0 = fmaxf(zn0, __expf(fminf(zn0, 0.f)) - 1.f);
            zn1 = fmaxf(zn1, __expf(fminf(zn1, 0.f)) - 1.f);
            zn2 = fmaxf(zn2, __expf(fminf(zn2, 0.f)) - 1.f);
            zn3 = fmaxf(zn3, __expf(fminf(zn3, 0.f)) - 1.f);
            uint2 u;
            u.x = f2bfu(zn0) | (f2bfu(zn1) << 16);
            u.y = f2bfu(zn2) | (f2bfu(zn3) << 16);
            *(uint2*)&zls[j][lane * 4 + 256 * s] = u;
        }
    }
    __syncthreads();

    // phase 2: MFMA. wave -> nt = r-tile, kt = K-half (12 steps each).
    int lq = lane >> 4, lr = lane & 15;
    int nt = wave & 1, kt = wave >> 1;
    const unsigned short* wrow = rwb + (size_t)(nt * 16 + lr) * 768;
    f32x4 acc = {0.f, 0.f, 0.f, 0.f};
#pragma unroll 4
    for (int st = 0; st < 12; st++) {
        int k0 = (kt * 12 + st) * 32 + lq * 8;
        short8 a = *(const short8*)&zls[lr][k0];
        short8 bf = *(const short8*)&wrow[k0];
        acc = __builtin_amdgcn_mfma_f32_16x16x32_bf16(a, bf, acc, 0, 0, 0);
    }
    __syncthreads();
    float* pacc = (float*)&zls[0][0];
#pragma unroll
    for (int q = 0; q < 4; q++)
        pacc[(kt * 2 + nt) * 256 + (lq * 4 + q) * 16 + lr] = acc[q];
    __syncthreads();

    // reduce K-halves + sigmoid + mask + store
    int j = tid >> 4, c = tid & 15;
    int jg = j0 + j;
    float mval = mask[i * 4 + b] * mask[jg * 4 + b];
    size_t obase = ((size_t)(i * 128 + jg) * 4 + b) * 24;
    float v0 = pacc[j * 16 + c] + pacc[512 + j * 16 + c];
    out[obase + c] = mval / (1.f + __expf(-(v0 + rel_b[c])));
    if (c < 8) {
        float v1 = pacc[256 + j * 16 + c] + pacc[768 + j * 16 + c];
        out[obase + 16 + c] = mval / (1.f + __expf(-(v1 + rel_b[16 + c])));
    }
}

// ---------------------------------------------------------------------------
extern "C" void kernel_launch(void* const* d_in, const int* in_sizes, int n_in,
                              void* d_out, int out_size, void* d_ws, size_t ws_size,
                              hipStream_t stream) {
    const float* h_re    = (const float*)d_in[0];
    const float* h_share = (const float*)d_in[1];
    const float* mask    = (const float*)d_in[2];
    const float* r_w     = (const float*)d_in[3];
    const float* r_b     = (const float*)d_in[4];
    const float* hid_w   = (const float*)d_in[5];
    const float* hid_b   = (const float*)d_in[6];
    const float* ln_g    = (const float*)d_in[7];
    const float* ln_b    = (const float*)d_in[8];
    const float* rel_w   = (const float*)d_in[9];
    const float* rel_b   = (const float*)d_in[10];
    float* out = (float*)d_out;

    float* ws   = (float*)d_ws;
    float* gpre = ws;                       // 393216 floats; reused as D later
    float* p12  = ws + 393216;              // 786432
    float* g    = ws + 1179648;             // 3072
    float* pg   = ws + 1182720;             // 3072
    float* su1  = ws + 1185792;             // 512
    float* su2  = ws + 1186304;             // 512
    float* sv1  = ws + 1186816;             // 512
    float* sv2  = ws + 1187328;             // 512
    unsigned short* rwb = (unsigned short*)(ws + 1187840);  // 24576 shorts
    float* D    = gpre;                     // alias: gpre dead after kMaxG

    kPrep<<<96, 256, 0, stream>>>(rel_w, rwb);
    kAB<<<576, 256, 0, stream>>>(h_re, h_share, r_w, hid_w, gpre, p12);
    kMaxG<<<dim3(12, 4), 256, 0, stream>>>(gpre, r_b, g);
    kPg<<<dim3(12, 4), 256, 0, stream>>>(g, hid_w, hid_b, pg);
    kStats<<<256, 256, 0, stream>>>(p12, pg, su1, su2, sv1, sv2);
    kDot<<<dim3(4, 8, 4), 256, 0, stream>>>(p12, pg, D);
    kC<<<dim3(L, B, 8), 256, 0, stream>>>(p12, pg, ln_g, ln_b, rwb, rel_b,
                                          su1, su2, sv1, sv2, D, mask, out);
}

// Round 6
// 113.358 us; speedup vs baseline: 5.8586x; 1.0671x over previous
//
#include <hip/hip_runtime.h>
#include <hip/hip_bf16.h>
#include <math.h>

#define L 128
#define B 4
#define H 768
#define LN_EPS 1e-5f

typedef __attribute__((ext_vector_type(8))) short short8;
typedef __attribute__((ext_vector_type(4))) float f32x4;

static __device__ __forceinline__ unsigned f2bfu(float f) {
    unsigned u = __float_as_uint(f);
    return (u + 0x7FFFu + ((u >> 16) & 1u)) >> 16;
}
static __device__ __forceinline__ uint2 pk4(float4 v) {
    uint2 o;
    o.x = f2bfu(v.x) | (f2bfu(v.y) << 16);
    o.y = f2bfu(v.z) | (f2bfu(v.w) << 16);
    return o;
}
static __device__ __forceinline__ unsigned short f2b(float f) {
    union { __hip_bfloat16 h; unsigned short u; } cv;
    cv.h = __float2bfloat16(f);
    return cv.u;
}
static __device__ __forceinline__ float4 unpk4(uint2 p) {
    return make_float4(__uint_as_float(p.x << 16),
                       __uint_as_float(p.x & 0xffff0000u),
                       __uint_as_float(p.y << 16),
                       __uint_as_float(p.y & 0xffff0000u));
}
static __device__ __forceinline__ unsigned fkey(float x) {
    unsigned u = __float_as_uint(x);
    return (u >> 31) ? ~u : (u | 0x80000000u);
}

// ---------------------------------------------------------------------------
// kConv: one-shot converts (fp32 -> bf16) + gmax init. 793344 tasks of 4 elems.
//  hcat[512][1536] = [h_share|h_re]; rwB = r_w as-is; hwB[n][k] (n<768: w1 col n,
//  else w2 col n-768); rwbPad[32][768] rel_w zero-padded; gmax init 0.
// ---------------------------------------------------------------------------
__global__ __launch_bounds__(256) void kConv(const float* __restrict__ h_re,
                                             const float* __restrict__ h_share,
                                             const float* __restrict__ r_w,
                                             const float* __restrict__ hid_w,
                                             const float* __restrict__ rel_w,
                                             unsigned short* __restrict__ hcat,
                                             unsigned short* __restrict__ rwB,
                                             unsigned short* __restrict__ hwB,
                                             unsigned short* __restrict__ rwbPad,
                                             unsigned int* __restrict__ gmax) {
    int t = blockIdx.x * 256 + threadIdx.x;
    if (t < 196608) {                       // hcat
        int e = t * 4, m = e / 1536, k = e - m * 1536;
        const float* src = (k < 768) ? (h_share + (size_t)m * 768 + k)
                                     : (h_re + (size_t)m * 768 + k - 768);
        ((uint2*)hcat)[t] = pk4(*(const float4*)src);
    } else if (t < 491520) {                // rwB
        int t2 = t - 196608;
        ((uint2*)rwB)[t2] = pk4(((const float4*)r_w)[t2]);
    } else if (t < 786432) {                // hwB
        int t3 = t - 491520;
        int e = t3 * 4, n = e / 768, k = e - n * 768;
        const float* src = (n < 768) ? (hid_w + (size_t)n * 2304 + k)
                                     : (hid_w + (size_t)(n - 768) * 2304 + 768 + k);
        ((uint2*)hwB)[t3] = pk4(*(const float4*)src);
    } else if (t < 792576) {                // rwbPad
        int t4 = t - 786432, e = t4 * 4;
        uint2 o = make_uint2(0u, 0u);
        if (e < 18432) o = pk4(((const float4*)rel_w)[t4]);
        ((uint2*)rwbPad)[t4] = o;
    } else {                                // gmax init
        int t5 = t - 792576;
        ((uint4*)gmax)[t5] = make_uint4(0u, 0u, 0u, 0u);
    }
}

// ---------------------------------------------------------------------------
// kGemm: barrier-free register MFMA. Wave = 32m x 16n tile, K direct from global.
//  blocks 0..191  (A): C=gpre-max: atomicMax into gmax[b][n]; K=1536 (hcat full)
//  blocks 192..575(B): C=p12[512][1536]; K=768 (hcat cols 768..; hwB)
// ---------------------------------------------------------------------------
__global__ __launch_bounds__(256) void kGemm(const unsigned short* __restrict__ hcat,
                                             const unsigned short* __restrict__ rwB,
                                             const unsigned short* __restrict__ hwB,
                                             unsigned int* __restrict__ gmax,
                                             float* __restrict__ p12) {
    int id = blockIdx.x, tid = threadIdx.x;
    int lane = tid & 63, wave = tid >> 6, lq = lane >> 4, lr = lane & 15;
    bool isA = id < 192;
    int bm, nbase, ksteps, kbeg, wstride;
    const unsigned short* Wb;
    if (isA) {
        bm = id & 15; nbase = (id >> 4) * 64 + wave * 16;
        Wb = rwB; wstride = 1536; ksteps = 48; kbeg = 0;
    } else {
        int id2 = id - 192;
        bm = id2 & 15; nbase = (id2 >> 4) * 64 + wave * 16;
        Wb = hwB; wstride = 768; ksteps = 24; kbeg = 768;
    }
    int m0 = bm * 32;
    const unsigned short* a0r = hcat + (size_t)(m0 + lr) * 1536 + kbeg + lq * 8;
    const unsigned short* a1r = hcat + (size_t)(m0 + 16 + lr) * 1536 + kbeg + lq * 8;
    const unsigned short* wr  = Wb + (size_t)(nbase + lr) * wstride + lq * 8;
    f32x4 acc0 = {0.f, 0.f, 0.f, 0.f}, acc1 = {0.f, 0.f, 0.f, 0.f};
#pragma unroll 4
    for (int s = 0; s < ksteps; s++) {
        short8 a0 = *(const short8*)(a0r + s * 32);
        short8 a1 = *(const short8*)(a1r + s * 32);
        short8 w  = *(const short8*)(wr + s * 32);
        acc0 = __builtin_amdgcn_mfma_f32_16x16x32_bf16(a0, w, acc0, 0, 0, 0);
        acc1 = __builtin_amdgcn_mfma_f32_16x16x32_bf16(a1, w, acc1, 0, 0, 0);
    }
    if (isA) {
#pragma unroll
        for (int q = 0; q < 4; q++) {
            atomicMax(&gmax[((m0 + lq * 4 + q) & 3) * 768 + nbase + lr], fkey(acc0[q]));
            atomicMax(&gmax[((m0 + 16 + lq * 4 + q) & 3) * 768 + nbase + lr], fkey(acc1[q]));
        }
    } else {
#pragma unroll
        for (int q = 0; q < 4; q++) {
            p12[(size_t)(m0 + lq * 4 + q) * 1536 + nbase + lr] = acc0[q];
            p12[(size_t)(m0 + 16 + lq * 4 + q) * 1536 + nbase + lr] = acc1[q];
        }
    }
}

// ---------------------------------------------------------------------------
// kPg: decode gmax -> g = tanh(max + r_b) in LDS, then pg[b][k]. grid (12,4).
// ---------------------------------------------------------------------------
__global__ __launch_bounds__(256) void kPg(const unsigned int* __restrict__ gmax,
                                           const float* __restrict__ r_b,
                                           const float* __restrict__ hid_w,
                                           const float* __restrict__ hid_b,
                                           float* __restrict__ pg) {
    __shared__ float sg[768];
    __shared__ float sp[4][64];
    int kt = blockIdx.x, b = blockIdx.y, tid = threadIdx.x;
    for (int v = tid; v < 768; v += 256) {
        unsigned key = gmax[b * 768 + v];
        unsigned bits = (key & 0x80000000u) ? (key & 0x7FFFFFFFu) : ~key;
        sg[v] = tanhf(__uint_as_float(bits) + r_b[v]);
    }
    __syncthreads();
    int kk = tid & 63, hc = tid >> 6;
    int k = kt * 64 + kk;
    const float4* w4 = (const float4*)hid_w;
    const float4* g4 = (const float4*)sg;
    float acc = 0.f;
    for (int h = hc * 48; h < hc * 48 + 48; h++) {
        float4 gv = g4[h];
        float4 wv = w4[(size_t)k * 576 + 384 + h];
        acc += gv.x * wv.x + gv.y * wv.y + gv.z * wv.z + gv.w * wv.w;
    }
    sp[hc][kk] = acc;
    __syncthreads();
    if (hc == 0)
        pg[b * 768 + k] = sp[0][kk] + sp[1][kk] + sp[2][kk] + sp[3][kk] + hid_b[k];
}

// ---------------------------------------------------------------------------
// kStatsB: row sums/sumsq of u=p1+pg (rows 0..511) and v=p2 (512..1023),
// plus bf16 copies ub16[b][i][k] / vb16[b][j][k]. 256 blocks, 1 wave/row.
// ---------------------------------------------------------------------------
__global__ __launch_bounds__(256) void kStatsB(const float* __restrict__ p12,
                                               const float* __restrict__ pg,
                                               float* __restrict__ su1,
                                               float* __restrict__ su2,
                                               float* __restrict__ sv1,
                                               float* __restrict__ sv2,
                                               unsigned short* __restrict__ ub16,
                                               unsigned short* __restrict__ vb16) {
    int row = blockIdx.x * 4 + (threadIdx.x >> 6);
    int lane = threadIdx.x & 63;
    bool isU = row < 512;
    int m = isU ? row : row - 512;
    const float4* src = (const float4*)(p12 + (size_t)m * 1536 + (isU ? 0 : 768));
    const float4* pg4 = (const float4*)(pg + (m & 3) * 768);
    unsigned short* dst = (isU ? ub16 : vb16) + (size_t)(m & 3) * 98304 + (size_t)(m >> 2) * 768;
    float s1 = 0.f, s2 = 0.f;
#pragma unroll
    for (int s = 0; s < 3; s++) {
        int c = lane + 64 * s;
        float4 v = src[c];
        if (isU) {
            float4 p = pg4[c];
            v.x += p.x; v.y += p.y; v.z += p.z; v.w += p.w;
        }
        s1 += v.x + v.y + v.z + v.w;
        s2 += v.x * v.x + v.y * v.y + v.z * v.z + v.w * v.w;
        ((uint2*)dst)[c] = pk4(v);
    }
#pragma unroll
    for (int off = 32; off > 0; off >>= 1) {
        s1 += __shfl_xor(s1, off, 64);
        s2 += __shfl_xor(s2, off, 64);
    }
    if (lane == 0) {
        if (isU) { su1[m] = s1; su2[m] = s2; }
        else     { sv1[m] = s1; sv2[m] = s2; }
    }
}

// ---------------------------------------------------------------------------
// kDotM: D[b][i][j] = dot(u_i, v_j) via bf16 MFMA. grid (4 i-tiles, 2 j-halves, 4 b).
// ---------------------------------------------------------------------------
__global__ __launch_bounds__(256) void kDotM(const unsigned short* __restrict__ ub16,
                                             const unsigned short* __restrict__ vb16,
                                             float* __restrict__ D) {
    int i0 = blockIdx.x * 32, j0 = blockIdx.y * 64, b = blockIdx.z;
    int tid = threadIdx.x, lane = tid & 63, wave = tid >> 6;
    int lq = lane >> 4, lr = lane & 15;
    int jb = j0 + wave * 16;
    const unsigned short* a0r = ub16 + (size_t)b * 98304 + (size_t)(i0 + lr) * 768 + lq * 8;
    const unsigned short* a1r = a0r + 16 * 768;
    const unsigned short* wr  = vb16 + (size_t)b * 98304 + (size_t)(jb + lr) * 768 + lq * 8;
    f32x4 acc0 = {0.f, 0.f, 0.f, 0.f}, acc1 = {0.f, 0.f, 0.f, 0.f};
#pragma unroll 4
    for (int s = 0; s < 24; s++) {
        short8 a0 = *(const short8*)(a0r + s * 32);
        short8 a1 = *(const short8*)(a1r + s * 32);
        short8 w  = *(const short8*)(wr + s * 32);
        acc0 = __builtin_amdgcn_mfma_f32_16x16x32_bf16(a0, w, acc0, 0, 0, 0);
        acc1 = __builtin_amdgcn_mfma_f32_16x16x32_bf16(a1, w, acc1, 0, 0, 0);
    }
#pragma unroll
    for (int q = 0; q < 4; q++) {
        D[b * 16384 + (i0 + lq * 4 + q) * 128 + jb + lr] = acc0[q];
        D[b * 16384 + (i0 + 16 + lq * 4 + q) * 128 + jb + lr] = acc1[q];
    }
}

// ---------------------------------------------------------------------------
// kC: block (i, b, jg) -> 32 j's, 512 thr (8 waves). LDS zls 32x776 bf16.
// Phase1: LN+ELU (stats precomputed, 1 fma/elem), bf16 in/out.
// Phase2: MFMA, wave=(nt, K-quarter), W-frag reused for 2 j-tiles; LDS reduce.
// ---------------------------------------------------------------------------
__global__ __launch_bounds__(512) void kC(const unsigned short* __restrict__ ub16,
                                          const unsigned short* __restrict__ vb16,
                                          const float* __restrict__ ln_g,
                                          const float* __restrict__ ln_b,
                                          const unsigned short* __restrict__ rwbPad,
                                          const float* __restrict__ rel_b,
                                          const float* __restrict__ su1,
                                          const float* __restrict__ su2,
                                          const float* __restrict__ sv1,
                                          const float* __restrict__ sv2,
                                          const float* __restrict__ D,
                                          const float* __restrict__ mask,
                                          float* __restrict__ out) {
    __shared__ unsigned short zls[32][776];
    __shared__ float smu[32], srs[32];
    int i = blockIdx.x, b = blockIdx.y, j0 = blockIdx.z * 32;
    int tid = threadIdx.x, lane = tid & 63, wave = tid >> 6;

    if (tid < 32) {
        int jg = j0 + tid;
        float mu = (su1[i * 4 + b] + sv1[jg * 4 + b]) * (1.f / 768.f);
        float ms = (su2[i * 4 + b] + 2.f * D[b * 16384 + i * 128 + jg] + sv2[jg * 4 + b])
                   * (1.f / 768.f);
        smu[tid] = mu;
        srs[tid] = rsqrtf(ms - mu * mu + LN_EPS);
    }
    const uint2* ur = (const uint2*)(ub16 + (size_t)b * 98304 + (size_t)i * 768);
    const float4* lg4 = (const float4*)ln_g;
    const float4* lb4 = (const float4*)ln_b;
    float4 uu[3], gg[3], bb[3];
#pragma unroll
    for (int s = 0; s < 3; s++) {
        int c = lane + 64 * s;
        uu[s] = unpk4(ur[c]);
        gg[s] = lg4[c];
        bb[s] = lb4[c];
    }
    __syncthreads();

#pragma unroll
    for (int jj = 0; jj < 4; jj++) {
        int j = wave * 4 + jj;
        float mu = smu[j], rs = srs[j];
        const uint2* vr = (const uint2*)(vb16 + (size_t)b * 98304 + (size_t)(j0 + j) * 768);
        uint2* zrow = (uint2*)&zls[j][0];
#pragma unroll
        for (int s = 0; s < 3; s++) {
            int c = lane + 64 * s;
            float4 vv = unpk4(vr[c]);
            float A0 = rs * gg[s].x, A1 = rs * gg[s].y, A2 = rs * gg[s].z, A3 = rs * gg[s].w;
            float C0 = fmaf(-mu, A0, bb[s].x), C1 = fmaf(-mu, A1, bb[s].y);
            float C2 = fmaf(-mu, A2, bb[s].z), C3 = fmaf(-mu, A3, bb[s].w);
            float z0 = fmaf(uu[s].x + vv.x, A0, C0);
            float z1 = fmaf(uu[s].y + vv.y, A1, C1);
            float z2 = fmaf(uu[s].z + vv.z, A2, C2);
            float z3 = fmaf(uu[s].w + vv.w, A3, C3);
            z0 = fmaxf(z0, __expf(fminf(z0, 0.f)) - 1.f);
            z1 = fmaxf(z1, __expf(fminf(z1, 0.f)) - 1.f);
            z2 = fmaxf(z2, __expf(fminf(z2, 0.f)) - 1.f);
            z3 = fmaxf(z3, __expf(fminf(z3, 0.f)) - 1.f);
            uint2 o;
            o.x = (unsigned)f2b(z0) | ((unsigned)f2b(z1) << 16);
            o.y = (unsigned)f2b(z2) | ((unsigned)f2b(z3) << 16);
            zrow[c] = o;
        }
    }
    __syncthreads();

    // phase 2: wave = (nt = w&1, kq = w>>1). 6 K-steps, 2 j-tiles per W-frag.
    int lq = lane >> 4, lr = lane & 15;
    int nt = wave & 1, kq = wave >> 1;
    const unsigned short* wrow = rwbPad + (size_t)(nt * 16 + lr) * 768 + kq * 192 + lq * 8;
    f32x4 accA = {0.f, 0.f, 0.f, 0.f}, accB = {0.f, 0.f, 0.f, 0.f};
#pragma unroll
    for (int st = 0; st < 6; st++) {
        int ko = kq * 192 + st * 32 + lq * 8;
        short8 w  = *(const short8*)(wrow + st * 32);
        short8 a0 = *(const short8*)&zls[lr][ko];
        short8 a1 = *(const short8*)&zls[16 + lr][ko];
        accA = __builtin_amdgcn_mfma_f32_16x16x32_bf16(a0, w, accA, 0, 0, 0);
        accB = __builtin_amdgcn_mfma_f32_16x16x32_bf16(a1, w, accB, 0, 0, 0);
    }
    __syncthreads();
    float* pacc = (float*)&zls[0][0];
#pragma unroll
    for (int q = 0; q < 4; q++) {
        pacc[((kq * 2 + nt) * 2 + 0) * 256 + (lq * 4 + q) * 16 + lr] = accA[q];
        pacc[((kq * 2 + nt) * 2 + 1) * 256 + (lq * 4 + q) * 16 + lr] = accB[q];
    }
    __syncthreads();

    int j = tid >> 4, c = tid & 15;
    int jgl = j0 + j, jt = j >> 4, row = j & 15;
    float mval = mask[i * 4 + b] * mask[jgl * 4 + b];
    size_t ob = ((size_t)(i * 128 + jgl) * 4 + b) * 24;
    float v0 = 0.f, v1 = 0.f;
#pragma unroll
    for (int k2 = 0; k2 < 4; k2++) {
        v0 += pacc[((k2 * 2 + 0) * 2 + jt) * 256 + row * 16 + c];
        v1 += pacc[((k2 * 2 + 1) * 2 + jt) * 256 + row * 16 + c];
    }
    out[ob + c] = mval / (1.f + __expf(-(v0 + rel_b[c])));
    if (c < 8)
        out[ob + 16 + c] = mval / (1.f + __expf(-(v1 + rel_b[16 + c])));
}

// ---------------------------------------------------------------------------
extern "C" void kernel_launch(void* const* d_in, const int* in_sizes, int n_in,
                              void* d_out, int out_size, void* d_ws, size_t ws_size,
                              hipStream_t stream) {
    const float* h_re    = (const float*)d_in[0];
    const float* h_share = (const float*)d_in[1];
    const float* mask    = (const float*)d_in[2];
    const float* r_w     = (const float*)d_in[3];
    const float* r_b     = (const float*)d_in[4];
    const float* hid_w   = (const float*)d_in[5];
    const float* hid_b   = (const float*)d_in[6];
    const float* ln_g    = (const float*)d_in[7];
    const float* ln_b    = (const float*)d_in[8];
    const float* rel_w   = (const float*)d_in[9];
    const float* rel_b   = (const float*)d_in[10];
    float* out = (float*)d_out;

    float* ws = (float*)d_ws;
    unsigned short* hcat   = (unsigned short*)(ws);             // 393216 f
    unsigned short* rwB    = (unsigned short*)(ws + 393216);    // 589824 f
    unsigned short* hwB    = (unsigned short*)(ws + 983040);    // 589824 f
    float*          p12    = ws + 1572864;                      // 786432 f
    float*          pg     = ws + 2359296;                      // 3072 f
    unsigned int*   gmax   = (unsigned int*)(ws + 2362368);     // 3072
    float*          su1    = ws + 2365440;                      // 512
    float*          su2    = ws + 2365952;
    float*          sv1    = ws + 2366464;
    float*          sv2    = ws + 2366976;
    unsigned short* rwbPad = (unsigned short*)(ws + 2367488);   // 12288 f
    // aliases into rwB/hwB region (dead after kGemm):
    unsigned short* ub16   = (unsigned short*)(ws + 393216);    // 196608 f
    unsigned short* vb16   = (unsigned short*)(ws + 589824);    // 196608 f
    float*          D      = ws + 786432;                       // 65536 f

    kConv<<<3099, 256, 0, stream>>>(h_re, h_share, r_w, hid_w, rel_w,
                                    hcat, rwB, hwB, rwbPad, gmax);
    kGemm<<<576, 256, 0, stream>>>(hcat, rwB, hwB, gmax, p12);
    kPg<<<dim3(12, 4), 256, 0, stream>>>(gmax, r_b, hid_w, hid_b, pg);
    kStatsB<<<256, 256, 0, stream>>>(p12, pg, su1, su2, sv1, sv2, ub16, vb16);
    kDotM<<<dim3(4, 2, 4), 256, 0, stream>>>(ub16, vb16, D);
    kC<<<dim3(L, B, 4), 512, 0, stream>>>(ub16, vb16, ln_g, ln_b, rwbPad, rel_b,
                                          su1, su2, sv1, sv2, D, mask, out);
}

// Round 7
// 86.992 us; speedup vs baseline: 7.6342x; 1.3031x over previous
//
#include <hip/hip_runtime.h>
#include <hip/hip_bf16.h>
#include <math.h>

#define L 128
#define B 4
#define H 768
#define LN_EPS 1e-5f

typedef __attribute__((ext_vector_type(8))) short short8;
typedef __attribute__((ext_vector_type(4))) float f32x4;

static __device__ __forceinline__ unsigned f2bfu(float f) {
    unsigned u = __float_as_uint(f);
    return (u + 0x7FFFu + ((u >> 16) & 1u)) >> 16;
}
static __device__ __forceinline__ uint2 pk4(float4 v) {
    uint2 o;
    o.x = f2bfu(v.x) | (f2bfu(v.y) << 16);
    o.y = f2bfu(v.z) | (f2bfu(v.w) << 16);
    return o;
}
static __device__ __forceinline__ unsigned short f2b(float f) {
    union { __hip_bfloat16 h; unsigned short u; } cv;
    cv.h = __float2bfloat16(f);
    return cv.u;
}
static __device__ __forceinline__ float4 unpk4(uint2 p) {
    return make_float4(__uint_as_float(p.x << 16),
                       __uint_as_float(p.x & 0xffff0000u),
                       __uint_as_float(p.y << 16),
                       __uint_as_float(p.y & 0xffff0000u));
}
static __device__ __forceinline__ unsigned fkey(float x) {
    unsigned u = __float_as_uint(x);
    return (u >> 31) ? ~u : (u | 0x80000000u);
}

// ---------------------------------------------------------------------------
// kConv: fp32 -> bf16 conversions, emitted in MFMA-fragment-linear packed
// layout so kGemm's loads are fully coalesced.
//   apack [32 mt][48 ks][64 lane][8]  : Acat=[h_share|h_re], frag for mfma A
//   wpackA[48 nt][48 ks][64 lane][8]  : r_w rows
//   wpackB[96 nt][24 ks][64 lane][8]  : hid_w cols (n<768: w1, else w2)
//   rwbPad[32][768]                   : rel_w zero-padded
//   gmax init 0
// fragment element (lane,e): row = 16*tile + (lane&15), k = 32*ks + (lane>>4)*8 + e
// ---------------------------------------------------------------------------
__global__ __launch_bounds__(256) void kConv(const float* __restrict__ h_re,
                                             const float* __restrict__ h_share,
                                             const float* __restrict__ r_w,
                                             const float* __restrict__ hid_w,
                                             const float* __restrict__ rel_w,
                                             unsigned short* __restrict__ apack,
                                             unsigned short* __restrict__ wpackA,
                                             unsigned short* __restrict__ wpackB,
                                             unsigned short* __restrict__ rwbPad,
                                             unsigned int* __restrict__ gmax) {
    int t = blockIdx.x * 256 + threadIdx.x;
    if (t < 196608) {                        // apack
        int o = t * 4;
        int e8 = o & 7, lane = (o >> 3) & 63, grp = o >> 9;
        int ks = grp % 48, mt = grp / 48;
        int m = mt * 16 + (lane & 15);
        int k = ks * 32 + (lane >> 4) * 8 + e8;
        const float* src = (k < 768) ? (h_share + (size_t)m * 768 + k)
                                     : (h_re + (size_t)m * 768 + (k - 768));
        ((uint2*)apack)[t] = pk4(*(const float4*)src);
    } else if (t < 491520) {                 // wpackA
        int t2 = t - 196608, o = t2 * 4;
        int e8 = o & 7, lane = (o >> 3) & 63, grp = o >> 9;
        int ks = grp % 48, nt = grp / 48;
        int n = nt * 16 + (lane & 15);
        int k = ks * 32 + (lane >> 4) * 8 + e8;
        ((uint2*)wpackA)[t2] = pk4(*(const float4*)(r_w + (size_t)n * 1536 + k));
    } else if (t < 786432) {                 // wpackB
        int t3 = t - 491520, o = t3 * 4;
        int e8 = o & 7, lane = (o >> 3) & 63, grp = o >> 9;
        int ks = grp % 24, nt = grp / 24;
        int n = nt * 16 + (lane & 15);
        int k = ks * 32 + (lane >> 4) * 8 + e8;
        int half = (n >= 768) ? 1 : 0;
        const float* src = hid_w + (size_t)(n - half * 768) * 2304 + half * 768 + k;
        ((uint2*)wpackB)[t3] = pk4(*(const float4*)src);
    } else if (t < 792576) {                 // rwbPad
        int t4 = t - 786432, e = t4 * 4;
        uint2 o = make_uint2(0u, 0u);
        if (e < 18432) o = pk4(((const float4*)rel_w)[t4]);
        ((uint2*)rwbPad)[t4] = o;
    } else {                                 // gmax init
        int t5 = t - 792576;
        ((uint4*)gmax)[t5] = make_uint4(0u, 0u, 0u, 0u);
    }
}

// ---------------------------------------------------------------------------
// kGemm: 1-wave blocks, 32m x 32n per wave, packed coalesced operands.
//  blocks 0..383  (A): K=48 steps, atomicMax into gmax[b][n]
//  blocks 384..1151(B): K=24 steps (apack ks 24..47), writes p12[512][1536]
// ---------------------------------------------------------------------------
template<int KS>
static __device__ __forceinline__ void gemm_tile(const unsigned short* __restrict__ ap,
                                                 const unsigned short* __restrict__ wr,
                                                 f32x4 acc[2][2]) {
#pragma unroll 4
    for (int s = 0; s < KS; s++) {
        short8 a0 = *(const short8*)(ap + (size_t)s * 512);
        short8 a1 = *(const short8*)(ap + (size_t)(48 + s) * 512);
        short8 w0 = *(const short8*)(wr + (size_t)s * 512);
        short8 w1 = *(const short8*)(wr + (size_t)(KS + s) * 512);
        acc[0][0] = __builtin_amdgcn_mfma_f32_16x16x32_bf16(a0, w0, acc[0][0], 0, 0, 0);
        acc[0][1] = __builtin_amdgcn_mfma_f32_16x16x32_bf16(a0, w1, acc[0][1], 0, 0, 0);
        acc[1][0] = __builtin_amdgcn_mfma_f32_16x16x32_bf16(a1, w0, acc[1][0], 0, 0, 0);
        acc[1][1] = __builtin_amdgcn_mfma_f32_16x16x32_bf16(a1, w1, acc[1][1], 0, 0, 0);
    }
}

__global__ __launch_bounds__(64) void kGemm(const unsigned short* __restrict__ apack,
                                            const unsigned short* __restrict__ wpackA,
                                            const unsigned short* __restrict__ wpackB,
                                            unsigned int* __restrict__ gmax,
                                            float* __restrict__ p12) {
    int id = blockIdx.x;
    int lane = threadIdx.x;
    int lq = lane >> 4, lr = lane & 15;
    f32x4 acc[2][2] = {{{0.f,0.f,0.f,0.f},{0.f,0.f,0.f,0.f}},
                       {{0.f,0.f,0.f,0.f},{0.f,0.f,0.f,0.f}}};
    if (id < 384) {
        int mt0 = (id / 24) * 2, nt0 = (id % 24) * 2;
        const unsigned short* ap = apack + (size_t)mt0 * 48 * 512 + lane * 8;
        const unsigned short* wr = wpackA + (size_t)nt0 * 48 * 512 + lane * 8;
        gemm_tile<48>(ap, wr, acc);
#pragma unroll
        for (int mi = 0; mi < 2; mi++)
#pragma unroll
            for (int ni = 0; ni < 2; ni++)
#pragma unroll
                for (int q = 0; q < 4; q++) {
                    int m = (mt0 + mi) * 16 + lq * 4 + q;
                    int n = (nt0 + ni) * 16 + lr;
                    atomicMax(&gmax[(m & 3) * 768 + n], fkey(acc[mi][ni][q]));
                }
    } else {
        int id2 = id - 384;
        int mt0 = (id2 / 48) * 2, nt0 = (id2 % 48) * 2;
        const unsigned short* ap = apack + ((size_t)mt0 * 48 + 24) * 512 + lane * 8;
        const unsigned short* wr = wpackB + (size_t)nt0 * 24 * 512 + lane * 8;
        gemm_tile<24>(ap, wr, acc);
#pragma unroll
        for (int mi = 0; mi < 2; mi++)
#pragma unroll
            for (int ni = 0; ni < 2; ni++)
#pragma unroll
                for (int q = 0; q < 4; q++) {
                    int m = (mt0 + mi) * 16 + lq * 4 + q;
                    int n = (nt0 + ni) * 16 + lr;
                    p12[(size_t)m * 1536 + n] = acc[mi][ni][q];
                }
    }
}

// ---------------------------------------------------------------------------
// kPg: decode gmax -> g = tanh(max + r_b) in LDS, then pg[b][k]. grid (12,4).
// ---------------------------------------------------------------------------
__global__ __launch_bounds__(256) void kPg(const unsigned int* __restrict__ gmax,
                                           const float* __restrict__ r_b,
                                           const float* __restrict__ hid_w,
                                           const float* __restrict__ hid_b,
                                           float* __restrict__ pg) {
    __shared__ float sg[768];
    __shared__ float sp[4][64];
    int kt = blockIdx.x, b = blockIdx.y, tid = threadIdx.x;
    for (int v = tid; v < 768; v += 256) {
        unsigned key = gmax[b * 768 + v];
        unsigned bits = (key & 0x80000000u) ? (key & 0x7FFFFFFFu) : ~key;
        sg[v] = tanhf(__uint_as_float(bits) + r_b[v]);
    }
    __syncthreads();
    int kk = tid & 63, hc = tid >> 6;
    int k = kt * 64 + kk;
    const float4* w4 = (const float4*)hid_w;
    const float4* g4 = (const float4*)sg;
    float acc = 0.f;
    for (int h = hc * 48; h < hc * 48 + 48; h++) {
        float4 gv = g4[h];
        float4 wv = w4[(size_t)k * 576 + 384 + h];
        acc += gv.x * wv.x + gv.y * wv.y + gv.z * wv.z + gv.w * wv.w;
    }
    sp[hc][kk] = acc;
    __syncthreads();
    if (hc == 0)
        pg[b * 768 + k] = sp[0][kk] + sp[1][kk] + sp[2][kk] + sp[3][kk] + hid_b[k];
}

// ---------------------------------------------------------------------------
// kStatsB: row sums/sumsq of u=p1+pg (rows 0..511) and v=p2 (512..1023),
// plus bf16 copies ub16[b][i][k] / vb16[b][j][k]. 256 blocks, 1 wave/row.
// ---------------------------------------------------------------------------
__global__ __launch_bounds__(256) void kStatsB(const float* __restrict__ p12,
                                               const float* __restrict__ pg,
                                               float* __restrict__ su1,
                                               float* __restrict__ su2,
                                               float* __restrict__ sv1,
                                               float* __restrict__ sv2,
                                               unsigned short* __restrict__ ub16,
                                               unsigned short* __restrict__ vb16) {
    int row = blockIdx.x * 4 + (threadIdx.x >> 6);
    int lane = threadIdx.x & 63;
    bool isU = row < 512;
    int m = isU ? row : row - 512;
    const float4* src = (const float4*)(p12 + (size_t)m * 1536 + (isU ? 0 : 768));
    const float4* pg4 = (const float4*)(pg + (m & 3) * 768);
    unsigned short* dst = (isU ? ub16 : vb16) + (size_t)(m & 3) * 98304 + (size_t)(m >> 2) * 768;
    float s1 = 0.f, s2 = 0.f;
#pragma unroll
    for (int s = 0; s < 3; s++) {
        int c = lane + 64 * s;
        float4 v = src[c];
        if (isU) {
            float4 p = pg4[c];
            v.x += p.x; v.y += p.y; v.z += p.z; v.w += p.w;
        }
        s1 += v.x + v.y + v.z + v.w;
        s2 += v.x * v.x + v.y * v.y + v.z * v.z + v.w * v.w;
        ((uint2*)dst)[c] = pk4(v);
    }
#pragma unroll
    for (int off = 32; off > 0; off >>= 1) {
        s1 += __shfl_xor(s1, off, 64);
        s2 += __shfl_xor(s2, off, 64);
    }
    if (lane == 0) {
        if (isU) { su1[m] = s1; su2[m] = s2; }
        else     { sv1[m] = s1; sv2[m] = s2; }
    }
}

// ---------------------------------------------------------------------------
// kDotM: D[b][i][j] = dot(u_i, v_j) via bf16 MFMA. grid (4 i-tiles, 2 j-halves, 4 b).
// ---------------------------------------------------------------------------
__global__ __launch_bounds__(256) void kDotM(const unsigned short* __restrict__ ub16,
                                             const unsigned short* __restrict__ vb16,
                                             float* __restrict__ D) {
    int i0 = blockIdx.x * 32, j0 = blockIdx.y * 64, b = blockIdx.z;
    int tid = threadIdx.x, lane = tid & 63, wave = tid >> 6;
    int lq = lane >> 4, lr = lane & 15;
    int jb = j0 + wave * 16;
    const unsigned short* a0r = ub16 + (size_t)b * 98304 + (size_t)(i0 + lr) * 768 + lq * 8;
    const unsigned short* a1r = a0r + 16 * 768;
    const unsigned short* wr  = vb16 + (size_t)b * 98304 + (size_t)(jb + lr) * 768 + lq * 8;
    f32x4 acc0 = {0.f, 0.f, 0.f, 0.f}, acc1 = {0.f, 0.f, 0.f, 0.f};
#pragma unroll 4
    for (int s = 0; s < 24; s++) {
        short8 a0 = *(const short8*)(a0r + s * 32);
        short8 a1 = *(const short8*)(a1r + s * 32);
        short8 w  = *(const short8*)(wr + s * 32);
        acc0 = __builtin_amdgcn_mfma_f32_16x16x32_bf16(a0, w, acc0, 0, 0, 0);
        acc1 = __builtin_amdgcn_mfma_f32_16x16x32_bf16(a1, w, acc1, 0, 0, 0);
    }
#pragma unroll
    for (int q = 0; q < 4; q++) {
        D[b * 16384 + (i0 + lq * 4 + q) * 128 + jb + lr] = acc0[q];
        D[b * 16384 + (i0 + 16 + lq * 4 + q) * 128 + jb + lr] = acc1[q];
    }
}

// ---------------------------------------------------------------------------
// kC: block (i, b, jg) -> 32 j's, 512 thr (8 waves). LDS zls 32x776 bf16.
// Phase1: LN+ELU (stats precomputed, 1 fma/elem), bf16 in/out.
// Phase2: MFMA, wave=(nt, K-quarter), W-frag reused for 2 j-tiles; LDS reduce.
// ---------------------------------------------------------------------------
__global__ __launch_bounds__(512) void kC(const unsigned short* __restrict__ ub16,
                                          const unsigned short* __restrict__ vb16,
                                          const float* __restrict__ ln_g,
                                          const float* __restrict__ ln_b,
                                          const unsigned short* __restrict__ rwbPad,
                                          const float* __restrict__ rel_b,
                                          const float* __restrict__ su1,
                                          const float* __restrict__ su2,
                                          const float* __restrict__ sv1,
                                          const float* __restrict__ sv2,
                                          const float* __restrict__ D,
                                          const float* __restrict__ mask,
                                          float* __restrict__ out) {
    __shared__ unsigned short zls[32][776];
    __shared__ float smu[32], srs[32];
    int i = blockIdx.x, b = blockIdx.y, j0 = blockIdx.z * 32;
    int tid = threadIdx.x, lane = tid & 63, wave = tid >> 6;

    if (tid < 32) {
        int jg = j0 + tid;
        float mu = (su1[i * 4 + b] + sv1[jg * 4 + b]) * (1.f / 768.f);
        float ms = (su2[i * 4 + b] + 2.f * D[b * 16384 + i * 128 + jg] + sv2[jg * 4 + b])
                   * (1.f / 768.f);
        smu[tid] = mu;
        srs[tid] = rsqrtf(ms - mu * mu + LN_EPS);
    }
    const uint2* ur = (const uint2*)(ub16 + (size_t)b * 98304 + (size_t)i * 768);
    const float4* lg4 = (const float4*)ln_g;
    const float4* lb4 = (const float4*)ln_b;
    float4 uu[3], gg[3], bb[3];
#pragma unroll
    for (int s = 0; s < 3; s++) {
        int c = lane + 64 * s;
        uu[s] = unpk4(ur[c]);
        gg[s] = lg4[c];
        bb[s] = lb4[c];
    }
    __syncthreads();

#pragma unroll
    for (int jj = 0; jj < 4; jj++) {
        int j = wave * 4 + jj;
        float mu = smu[j], rs = srs[j];
        const uint2* vr = (const uint2*)(vb16 + (size_t)b * 98304 + (size_t)(j0 + j) * 768);
        uint2* zrow = (uint2*)&zls[j][0];
#pragma unroll
        for (int s = 0; s < 3; s++) {
            int c = lane + 64 * s;
            float4 vv = unpk4(vr[c]);
            float A0 = rs * gg[s].x, A1 = rs * gg[s].y, A2 = rs * gg[s].z, A3 = rs * gg[s].w;
            float C0 = fmaf(-mu, A0, bb[s].x), C1 = fmaf(-mu, A1, bb[s].y);
            float C2 = fmaf(-mu, A2, bb[s].z), C3 = fmaf(-mu, A3, bb[s].w);
            float z0 = fmaf(uu[s].x + vv.x, A0, C0);
            float z1 = fmaf(uu[s].y + vv.y, A1, C1);
            float z2 = fmaf(uu[s].z + vv.z, A2, C2);
            float z3 = fmaf(uu[s].w + vv.w, A3, C3);
            z0 = fmaxf(z0, __expf(fminf(z0, 0.f)) - 1.f);
            z1 = fmaxf(z1, __expf(fminf(z1, 0.f)) - 1.f);
            z2 = fmaxf(z2, __expf(fminf(z2, 0.f)) - 1.f);
            z3 = fmaxf(z3, __expf(fminf(z3, 0.f)) - 1.f);
            uint2 o;
            o.x = (unsigned)f2b(z0) | ((unsigned)f2b(z1) << 16);
            o.y = (unsigned)f2b(z2) | ((unsigned)f2b(z3) << 16);
            zrow[c] = o;
        }
    }
    __syncthreads();

    // phase 2: wave = (nt = w&1, kq = w>>1). 6 K-steps, 2 j-tiles per W-frag.
    int lq = lane >> 4, lr = lane & 15;
    int nt = wave & 1, kq = wave >> 1;
    const unsigned short* wrow = rwbPad + (size_t)(nt * 16 + lr) * 768 + kq * 192 + lq * 8;
    f32x4 accA = {0.f, 0.f, 0.f, 0.f}, accB = {0.f, 0.f, 0.f, 0.f};
#pragma unroll
    for (int st = 0; st < 6; st++) {
        int ko = kq * 192 + st * 32 + lq * 8;
        short8 w  = *(const short8*)(wrow + st * 32);
        short8 a0 = *(const short8*)&zls[lr][ko];
        short8 a1 = *(const short8*)&zls[16 + lr][ko];
        accA = __builtin_amdgcn_mfma_f32_16x16x32_bf16(a0, w, accA, 0, 0, 0);
        accB = __builtin_amdgcn_mfma_f32_16x16x32_bf16(a1, w, accB, 0, 0, 0);
    }
    __syncthreads();
    float* pacc = (float*)&zls[0][0];
#pragma unroll
    for (int q = 0; q < 4; q++) {
        pacc[((kq * 2 + nt) * 2 + 0) * 256 + (lq * 4 + q) * 16 + lr] = accA[q];
        pacc[((kq * 2 + nt) * 2 + 1) * 256 + (lq * 4 + q) * 16 + lr] = accB[q];
    }
    __syncthreads();

    int j = tid >> 4, c = tid & 15;
    int jgl = j0 + j, jt = j >> 4, row = j & 15;
    float mval = mask[i * 4 + b] * mask[jgl * 4 + b];
    size_t ob = ((size_t)(i * 128 + jgl) * 4 + b) * 24;
    float v0 = 0.f, v1 = 0.f;
#pragma unroll
    for (int k2 = 0; k2 < 4; k2++) {
        v0 += pacc[((k2 * 2 + 0) * 2 + jt) * 256 + row * 16 + c];
        v1 += pacc[((k2 * 2 + 1) * 2 + jt) * 256 + row * 16 + c];
    }
    out[ob + c] = mval / (1.f + __expf(-(v0 + rel_b[c])));
    if (c < 8)
        out[ob + 16 + c] = mval / (1.f + __expf(-(v1 + rel_b[16 + c])));
}

// ---------------------------------------------------------------------------
extern "C" void kernel_launch(void* const* d_in, const int* in_sizes, int n_in,
                              void* d_out, int out_size, void* d_ws, size_t ws_size,
                              hipStream_t stream) {
    const float* h_re    = (const float*)d_in[0];
    const float* h_share = (const float*)d_in[1];
    const float* mask    = (const float*)d_in[2];
    const float* r_w     = (const float*)d_in[3];
    const float* r_b     = (const float*)d_in[4];
    const float* hid_w   = (const float*)d_in[5];
    const float* hid_b   = (const float*)d_in[6];
    const float* ln_g    = (const float*)d_in[7];
    const float* ln_b    = (const float*)d_in[8];
    const float* rel_w   = (const float*)d_in[9];
    const float* rel_b   = (const float*)d_in[10];
    float* out = (float*)d_out;

    float* ws = (float*)d_ws;
    unsigned short* apack  = (unsigned short*)(ws);             // 393216 f
    unsigned short* wpackA = (unsigned short*)(ws + 393216);    // 589824 f
    unsigned short* wpackB = (unsigned short*)(ws + 983040);    // 589824 f
    float*          p12    = ws + 1572864;                      // 786432 f
    float*          pg     = ws + 2359296;                      // 3072 f
    unsigned int*   gmax   = (unsigned int*)(ws + 2362368);     // 3072
    float*          su1    = ws + 2365440;                      // 512
    float*          su2    = ws + 2365952;
    float*          sv1    = ws + 2366464;
    float*          sv2    = ws + 2366976;
    unsigned short* rwbPad = (unsigned short*)(ws + 2367488);   // 12288 f
    // aliases into wpackA/wpackB region (dead after kGemm):
    unsigned short* ub16   = (unsigned short*)(ws + 393216);    // 98304 f... (196608 f span)
    unsigned short* vb16   = (unsigned short*)(ws + 589824);
    float*          D      = ws + 786432;                       // 65536 f

    kConv<<<3099, 256, 0, stream>>>(h_re, h_share, r_w, hid_w, rel_w,
                                    apack, wpackA, wpackB, rwbPad, gmax);
    kGemm<<<1152, 64, 0, stream>>>(apack, wpackA, wpackB, gmax, p12);
    kPg<<<dim3(12, 4), 256, 0, stream>>>(gmax, r_b, hid_w, hid_b, pg);
    kStatsB<<<256, 256, 0, stream>>>(p12, pg, su1, su2, sv1, sv2, ub16, vb16);
    kDotM<<<dim3(4, 2, 4), 256, 0, stream>>>(ub16, vb16, D);
    kC<<<dim3(L, B, 4), 512, 0, stream>>>(ub16, vb16, ln_g, ln_b, rwbPad, rel_b,
                                          su1, su2, sv1, sv2, D, mask, out);
}

// Round 8
// 85.244 us; speedup vs baseline: 7.7907x; 1.0205x over previous
//
#include <hip/hip_runtime.h>
#include <hip/hip_bf16.h>
#include <math.h>

#define L 128
#define B 4
#define H 768
#define LN_EPS 1e-5f
#define XROWS 272            // [p1:0..127 | p2:128..255 | pg:256 | ones:257 | 0:258..271]
#define DSTRIDE 73984        // 272*272

typedef __attribute__((ext_vector_type(8))) short short8;
typedef __attribute__((ext_vector_type(4))) float f32x4;

static __device__ __forceinline__ unsigned f2bfu(float f) {
    unsigned u = __float_as_uint(f);
    return (u + 0x7FFFu + ((u >> 16) & 1u)) >> 16;
}
static __device__ __forceinline__ uint2 pk4(float4 v) {
    uint2 o;
    o.x = f2bfu(v.x) | (f2bfu(v.y) << 16);
    o.y = f2bfu(v.z) | (f2bfu(v.w) << 16);
    return o;
}
static __device__ __forceinline__ unsigned short f2b(float f) {
    union { __hip_bfloat16 h; unsigned short u; } cv;
    cv.h = __float2bfloat16(f);
    return cv.u;
}
static __device__ __forceinline__ float4 unpk4(uint2 p) {
    return make_float4(__uint_as_float(p.x << 16),
                       __uint_as_float(p.x & 0xffff0000u),
                       __uint_as_float(p.y << 16),
                       __uint_as_float(p.y & 0xffff0000u));
}
static __device__ __forceinline__ unsigned fkey(float x) {
    unsigned u = __float_as_uint(x);
    return (u >> 31) ? ~u : (u | 0x80000000u);
}

// ---------------------------------------------------------------------------
// kConv: all fp32->bf16 packing, coalesced READS + scattered 16B writes.
//  S1 apack [32mt][48ks][64lane][8]  S2 wpackA [48nt][48ks][64][8]
//  S3 wpackB [96nt][24ks][64][8]     S4 rwbPad[32][768]
//  S5 X rows 257..271 (ones/zeros)   S6 gmax=0
// ---------------------------------------------------------------------------
__global__ __launch_bounds__(256) void kConv(const float* __restrict__ h_re,
                                             const float* __restrict__ h_share,
                                             const float* __restrict__ r_w,
                                             const float* __restrict__ hid_w,
                                             const float* __restrict__ rel_w,
                                             unsigned short* __restrict__ apack,
                                             unsigned short* __restrict__ wpackA,
                                             unsigned short* __restrict__ wpackB,
                                             unsigned short* __restrict__ rwbPad,
                                             unsigned short* __restrict__ xb16,
                                             unsigned int* __restrict__ gmax) {
    int t = blockIdx.x * 256 + threadIdx.x;
    if (t >= 402816) return;
    if (t < 98304) {                          // apack: Acat=[h_share|h_re]
        int m = t / 192, oct = t % 192, k = oct * 8;
        const float* src = (k < 768) ? (h_share + (size_t)m * 768 + k)
                                     : (h_re + (size_t)m * 768 + k - 768);
        float4 x = *(const float4*)src, y = *(const float4*)(src + 4);
        int mt = m >> 4, lr = m & 15, ks = k >> 5, lq = (k >> 3) & 3;
        uint2* dst = (uint2*)(apack + (((size_t)mt * 48 + ks) * 64 + lq * 16 + lr) * 8);
        dst[0] = pk4(x); dst[1] = pk4(y);
    } else if (t < 245760) {                  // wpackA: r_w rows
        int t2 = t - 98304;
        int n = t2 / 192, oct = t2 % 192, k = oct * 8;
        const float* src = r_w + (size_t)n * 1536 + k;
        float4 x = *(const float4*)src, y = *(const float4*)(src + 4);
        int nt = n >> 4, lr = n & 15, ks = k >> 5, lq = (k >> 3) & 3;
        uint2* dst = (uint2*)(wpackA + (((size_t)nt * 48 + ks) * 64 + lq * 16 + lr) * 8);
        dst[0] = pk4(x); dst[1] = pk4(y);
    } else if (t < 393216) {                  // wpackB: hid_w rows (w1|w2)
        int t3 = t - 245760;
        int n = t3 / 96, oct = t3 % 96, k = oct * 8;
        int half = (n >= 768) ? 1 : 0;
        const float* src = hid_w + (size_t)(n - half * 768) * 2304 + half * 768 + k;
        float4 x = *(const float4*)src, y = *(const float4*)(src + 4);
        int nt = n >> 4, lr = n & 15, ks = k >> 5, lq = (k >> 3) & 3;
        uint2* dst = (uint2*)(wpackB + (((size_t)nt * 24 + ks) * 64 + lq * 16 + lr) * 8);
        dst[0] = pk4(x); dst[1] = pk4(y);
    } else if (t < 396288) {                  // rwbPad (row-major, zero-padded)
        int t4 = t - 393216;
        int r = t4 / 96, oct = t4 % 96, k = oct * 8;
        uint2 o0 = make_uint2(0u, 0u), o1 = o0;
        if (r < 24) {
            const float* src = rel_w + (size_t)r * 768 + k;
            o0 = pk4(*(const float4*)src);
            o1 = pk4(*(const float4*)(src + 4));
        }
        uint2* dst = (uint2*)(rwbPad + (size_t)r * 768 + k);
        dst[0] = o0; dst[1] = o1;
    } else if (t < 402048) {                  // X tail rows 257..271
        int t5 = t - 396288;
        int b = t5 / 1440, rem = t5 % 1440, row = 257 + rem / 96, oct = rem % 96;
        unsigned val = (row == 257) ? 0x3F803F80u : 0u;
        uint2* dst = (uint2*)(xb16 + ((size_t)b * XROWS + row) * 768 + oct * 8);
        dst[0] = make_uint2(val, val); dst[1] = make_uint2(val, val);
    } else {                                  // gmax zero (768 x uint4)
        int t6 = t - 402048;
        ((uint4*)gmax)[t6] = make_uint4(0u, 0u, 0u, 0u);
    }
}

// ---------------------------------------------------------------------------
// kGemm: 1-wave blocks, 32x32 per wave, packed coalesced operands.
//  blocks 0..383  (A): K=48 steps, atomicMax into gmax[b][n]
//  blocks 384..1151(B): K=24 steps, writes bf16 into X rows (p1/p2)
// ---------------------------------------------------------------------------
template<int KS>
static __device__ __forceinline__ void gemm_tile(const unsigned short* __restrict__ ap,
                                                 const unsigned short* __restrict__ wr,
                                                 f32x4 acc[2][2]) {
#pragma unroll 8
    for (int s = 0; s < KS; s++) {
        short8 a0 = *(const short8*)(ap + (size_t)s * 512);
        short8 a1 = *(const short8*)(ap + (size_t)(48 + s) * 512);
        short8 w0 = *(const short8*)(wr + (size_t)s * 512);
        short8 w1 = *(const short8*)(wr + (size_t)(KS + s) * 512);
        acc[0][0] = __builtin_amdgcn_mfma_f32_16x16x32_bf16(a0, w0, acc[0][0], 0, 0, 0);
        acc[0][1] = __builtin_amdgcn_mfma_f32_16x16x32_bf16(a0, w1, acc[0][1], 0, 0, 0);
        acc[1][0] = __builtin_amdgcn_mfma_f32_16x16x32_bf16(a1, w0, acc[1][0], 0, 0, 0);
        acc[1][1] = __builtin_amdgcn_mfma_f32_16x16x32_bf16(a1, w1, acc[1][1], 0, 0, 0);
    }
}

__global__ __launch_bounds__(64) void kGemm(const unsigned short* __restrict__ apack,
                                            const unsigned short* __restrict__ wpackA,
                                            const unsigned short* __restrict__ wpackB,
                                            unsigned int* __restrict__ gmax,
                                            unsigned short* __restrict__ xb16) {
    int id = blockIdx.x;
    int lane = threadIdx.x;
    int lq = lane >> 4, lr = lane & 15;
    f32x4 acc[2][2] = {{{0.f,0.f,0.f,0.f},{0.f,0.f,0.f,0.f}},
                       {{0.f,0.f,0.f,0.f},{0.f,0.f,0.f,0.f}}};
    if (id < 384) {
        int mt0 = (id / 24) * 2, nt0 = (id % 24) * 2;
        const unsigned short* ap = apack + (size_t)mt0 * 48 * 512 + lane * 8;
        const unsigned short* wr = wpackA + (size_t)nt0 * 48 * 512 + lane * 8;
        gemm_tile<48>(ap, wr, acc);
#pragma unroll
        for (int mi = 0; mi < 2; mi++)
#pragma unroll
            for (int ni = 0; ni < 2; ni++)
#pragma unroll
                for (int q = 0; q < 4; q++) {
                    int m = (mt0 + mi) * 16 + lq * 4 + q;
                    int n = (nt0 + ni) * 16 + lr;
                    atomicMax(&gmax[(m & 3) * 768 + n], fkey(acc[mi][ni][q]));
                }
    } else {
        int id2 = id - 384;
        int mt0 = (id2 / 48) * 2, nt0 = (id2 % 48) * 2;
        const unsigned short* ap = apack + ((size_t)mt0 * 48 + 24) * 512 + lane * 8;
        const unsigned short* wr = wpackB + (size_t)nt0 * 24 * 512 + lane * 8;
        gemm_tile<24>(ap, wr, acc);
#pragma unroll
        for (int mi = 0; mi < 2; mi++)
#pragma unroll
            for (int ni = 0; ni < 2; ni++)
#pragma unroll
                for (int q = 0; q < 4; q++) {
                    int m = (mt0 + mi) * 16 + lq * 4 + q;
                    int n = (nt0 + ni) * 16 + lr;
                    int b = m & 3, l = m >> 2;
                    size_t row = (n < 768) ? (size_t)l : (size_t)(128 + l);
                    int col = (n < 768) ? n : n - 768;
                    xb16[((size_t)b * XROWS + row) * 768 + col] = f2b(acc[mi][ni][q]);
                }
    }
}

// ---------------------------------------------------------------------------
// kPg: decode gmax -> g = tanh(max+r_b), pg = g.w3 + hid_b -> X row 256 (bf16)
// ---------------------------------------------------------------------------
__global__ __launch_bounds__(256) void kPg(const unsigned int* __restrict__ gmax,
                                           const float* __restrict__ r_b,
                                           const float* __restrict__ hid_w,
                                           const float* __restrict__ hid_b,
                                           unsigned short* __restrict__ xb16) {
    __shared__ float sg[768];
    __shared__ float sp[4][64];
    int kt = blockIdx.x, b = blockIdx.y, tid = threadIdx.x;
    for (int v = tid; v < 768; v += 256) {
        unsigned key = gmax[b * 768 + v];
        unsigned bits = (key & 0x80000000u) ? (key & 0x7FFFFFFFu) : ~key;
        sg[v] = tanhf(__uint_as_float(bits) + r_b[v]);
    }
    __syncthreads();
    int kk = tid & 63, hc = tid >> 6;
    int k = kt * 64 + kk;
    const float4* w4 = (const float4*)hid_w;
    const float4* g4 = (const float4*)sg;
    float acc = 0.f;
    for (int h = hc * 48; h < hc * 48 + 48; h++) {
        float4 gv = g4[h];
        float4 wv = w4[(size_t)k * 576 + 384 + h];
        acc += gv.x * wv.x + gv.y * wv.y + gv.z * wv.z + gv.w * wv.w;
    }
    sp[hc][kk] = acc;
    __syncthreads();
    if (hc == 0) {
        float pgv = sp[0][kk] + sp[1][kk] + sp[2][kk] + sp[3][kk] + hid_b[k];
        xb16[((size_t)b * XROWS + 256) * 768 + k] = f2b(pgv);
    }
}

// ---------------------------------------------------------------------------
// kGram: D[b] = X[b] . X[b]^T  (272x272, K=768) via MFMA. grid (17,17,4), 64 thr.
// Every LN statistic is a D entry (ones row 257, pg row 256, diag = sumsq).
// ---------------------------------------------------------------------------
__global__ __launch_bounds__(64) void kGram(const unsigned short* __restrict__ xb16,
                                            float* __restrict__ D) {
    int it = blockIdx.x, jt = blockIdx.y, b = blockIdx.z;
    int lane = threadIdx.x, lq = lane >> 4, lr = lane & 15;
    const unsigned short* ar = xb16 + ((size_t)b * XROWS + it * 16 + lr) * 768 + lq * 8;
    const unsigned short* wr = xb16 + ((size_t)b * XROWS + jt * 16 + lr) * 768 + lq * 8;
    f32x4 acc = {0.f, 0.f, 0.f, 0.f};
#pragma unroll 8
    for (int s = 0; s < 24; s++) {
        short8 a = *(const short8*)(ar + s * 32);
        short8 w = *(const short8*)(wr + s * 32);
        acc = __builtin_amdgcn_mfma_f32_16x16x32_bf16(a, w, acc, 0, 0, 0);
    }
    float* Db = D + (size_t)b * DSTRIDE;
#pragma unroll
    for (int q = 0; q < 4; q++)
        Db[(size_t)(it * 16 + lq * 4 + q) * XROWS + jt * 16 + lr] = acc[q];
}

// ---------------------------------------------------------------------------
// kC: block (i, b, jg) -> 32 j's, 512 thr (8 waves). LDS zls 32x776 bf16.
// Phase1: LN+ELU, all stats from D. Phase2: rel MFMA, K-split 4, LDS reduce.
// ---------------------------------------------------------------------------
__global__ __launch_bounds__(512) void kC(const unsigned short* __restrict__ xb16,
                                          const float* __restrict__ ln_g,
                                          const float* __restrict__ ln_b,
                                          const unsigned short* __restrict__ rwbPad,
                                          const float* __restrict__ rel_b,
                                          const float* __restrict__ D,
                                          const float* __restrict__ mask,
                                          float* __restrict__ out) {
    __shared__ unsigned short zls[32][776];
    __shared__ float smu[32], srs[32];
    int i = blockIdx.x, b = blockIdx.y, j0 = blockIdx.z * 32;
    int tid = threadIdx.x, lane = tid & 63, wave = tid >> 6;

    if (tid < 32) {
        const float* Db = D + (size_t)b * DSTRIDE;
        int vr = 128 + j0 + tid;
        float Su1 = Db[(size_t)i * XROWS + 257];
        float Su2 = Db[(size_t)i * XROWS + i];
        float up  = Db[(size_t)i * XROWS + 256];
        float Sp1 = Db[(size_t)256 * XROWS + 257];
        float Sp2 = Db[(size_t)256 * XROWS + 256];
        float Sv1 = Db[(size_t)vr * XROWS + 257];
        float Sv2 = Db[(size_t)vr * XROWS + vr];
        float Dij = Db[(size_t)i * XROWS + vr];
        float cvj = Db[(size_t)vr * XROWS + 256];
        float s1 = Su1 + Sp1 + Sv1;
        float s2 = Su2 + Sp2 + Sv2 + 2.f * (Dij + up + cvj);
        float mu = s1 * (1.f / 768.f);
        smu[tid] = mu;
        srs[tid] = rsqrtf(s2 * (1.f / 768.f) - mu * mu + LN_EPS);
    }
    const uint2* ur = (const uint2*)(xb16 + ((size_t)b * XROWS + i) * 768);
    const uint2* pr = (const uint2*)(xb16 + ((size_t)b * XROWS + 256) * 768);
    const float4* lg4 = (const float4*)ln_g;
    const float4* lb4 = (const float4*)ln_b;
    float4 t1[3], gg[3], bb[3];
#pragma unroll
    for (int s = 0; s < 3; s++) {
        int c = lane + 64 * s;
        float4 x = unpk4(ur[c]), y = unpk4(pr[c]);
        t1[s] = make_float4(x.x + y.x, x.y + y.y, x.z + y.z, x.w + y.w);
        gg[s] = lg4[c];
        bb[s] = lb4[c];
    }
    __syncthreads();

#pragma unroll
    for (int jj = 0; jj < 4; jj++) {
        int j = wave * 4 + jj;
        float mu = smu[j], rs = srs[j];
        const uint2* vr2 = (const uint2*)(xb16 + ((size_t)b * XROWS + 128 + j0 + j) * 768);
        uint2* zrow = (uint2*)&zls[j][0];
#pragma unroll
        for (int s = 0; s < 3; s++) {
            int c = lane + 64 * s;
            float4 vv = unpk4(vr2[c]);
            float A0 = rs * gg[s].x, A1 = rs * gg[s].y, A2 = rs * gg[s].z, A3 = rs * gg[s].w;
            float C0 = fmaf(-mu, A0, bb[s].x), C1 = fmaf(-mu, A1, bb[s].y);
            float C2 = fmaf(-mu, A2, bb[s].z), C3 = fmaf(-mu, A3, bb[s].w);
            float z0 = fmaf(t1[s].x + vv.x, A0, C0);
            float z1 = fmaf(t1[s].y + vv.y, A1, C1);
            float z2 = fmaf(t1[s].z + vv.z, A2, C2);
            float z3 = fmaf(t1[s].w + vv.w, A3, C3);
            z0 = fmaxf(z0, __expf(fminf(z0, 0.f)) - 1.f);
            z1 = fmaxf(z1, __expf(fminf(z1, 0.f)) - 1.f);
            z2 = fmaxf(z2, __expf(fminf(z2, 0.f)) - 1.f);
            z3 = fmaxf(z3, __expf(fminf(z3, 0.f)) - 1.f);
            uint2 o;
            o.x = (unsigned)f2b(z0) | ((unsigned)f2b(z1) << 16);
            o.y = (unsigned)f2b(z2) | ((unsigned)f2b(z3) << 16);
            zrow[c] = o;
        }
    }
    __syncthreads();

    // phase 2: wave = (nt = w&1, kq = w>>1). 6 K-steps, 2 j-tiles per W-frag.
    int lq = lane >> 4, lr = lane & 15;
    int nt = wave & 1, kq = wave >> 1;
    const unsigned short* wrow = rwbPad + (size_t)(nt * 16 + lr) * 768 + kq * 192 + lq * 8;
    f32x4 accA = {0.f, 0.f, 0.f, 0.f}, accB = {0.f, 0.f, 0.f, 0.f};
#pragma unroll
    for (int st = 0; st < 6; st++) {
        int ko = kq * 192 + st * 32 + lq * 8;
        short8 w  = *(const short8*)(wrow + st * 32);
        short8 a0 = *(const short8*)&zls[lr][ko];
        short8 a1 = *(const short8*)&zls[16 + lr][ko];
        accA = __builtin_amdgcn_mfma_f32_16x16x32_bf16(a0, w, accA, 0, 0, 0);
        accB = __builtin_amdgcn_mfma_f32_16x16x32_bf16(a1, w, accB, 0, 0, 0);
    }
    __syncthreads();
    float* pacc = (float*)&zls[0][0];
#pragma unroll
    for (int q = 0; q < 4; q++) {
        pacc[((kq * 2 + nt) * 2 + 0) * 256 + (lq * 4 + q) * 16 + lr] = accA[q];
        pacc[((kq * 2 + nt) * 2 + 1) * 256 + (lq * 4 + q) * 16 + lr] = accB[q];
    }
    __syncthreads();

    int j = tid >> 4, c = tid & 15;
    int jgl = j0 + j, jt = j >> 4, row = j & 15;
    float mval = mask[i * 4 + b] * mask[jgl * 4 + b];
    size_t ob = ((size_t)(i * 128 + jgl) * 4 + b) * 24;
    float v0 = 0.f, v1 = 0.f;
#pragma unroll
    for (int k2 = 0; k2 < 4; k2++) {
        v0 += pacc[((k2 * 2 + 0) * 2 + jt) * 256 + row * 16 + c];
        v1 += pacc[((k2 * 2 + 1) * 2 + jt) * 256 + row * 16 + c];
    }
    out[ob + c] = mval / (1.f + __expf(-(v0 + rel_b[c])));
    if (c < 8)
        out[ob + 16 + c] = mval / (1.f + __expf(-(v1 + rel_b[16 + c])));
}

// ---------------------------------------------------------------------------
extern "C" void kernel_launch(void* const* d_in, const int* in_sizes, int n_in,
                              void* d_out, int out_size, void* d_ws, size_t ws_size,
                              hipStream_t stream) {
    const float* h_re    = (const float*)d_in[0];
    const float* h_share = (const float*)d_in[1];
    const float* mask    = (const float*)d_in[2];
    const float* r_w     = (const float*)d_in[3];
    const float* r_b     = (const float*)d_in[4];
    const float* hid_w   = (const float*)d_in[5];
    const float* hid_b   = (const float*)d_in[6];
    const float* ln_g    = (const float*)d_in[7];
    const float* ln_b    = (const float*)d_in[8];
    const float* rel_w   = (const float*)d_in[9];
    const float* rel_b   = (const float*)d_in[10];
    float* out = (float*)d_out;

    float* ws = (float*)d_ws;
    unsigned short* apack  = (unsigned short*)(ws);             // 393216 f
    unsigned short* wpackA = (unsigned short*)(ws + 393216);    // 589824 f
    unsigned short* wpackB = (unsigned short*)(ws + 983040);    // 589824 f
    unsigned short* xb16   = (unsigned short*)(ws + 1572864);   // 417792 f (4*272*768 sh)
    float*          D      = ws + 1990656;                      // 295936 f
    unsigned int*   gmax   = (unsigned int*)(ws + 2286592);     // 3072
    unsigned short* rwbPad = (unsigned short*)(ws + 2289664);   // 12288 f

    kConv<<<1574, 256, 0, stream>>>(h_re, h_share, r_w, hid_w, rel_w,
                                    apack, wpackA, wpackB, rwbPad, xb16, gmax);
    kGemm<<<1152, 64, 0, stream>>>(apack, wpackA, wpackB, gmax, xb16);
    kPg<<<dim3(12, 4), 256, 0, stream>>>(gmax, r_b, hid_w, hid_b, xb16);
    kGram<<<dim3(17, 17, 4), 64, 0, stream>>>(xb16, D);
    kC<<<dim3(L, B, 4), 512, 0, stream>>>(xb16, ln_g, ln_b, rwbPad, rel_b,
                                          D, mask, out);
}

// Round 9
// 75.984 us; speedup vs baseline: 8.7403x; 1.1219x over previous
//
#include <hip/hip_runtime.h>
#include <hip/hip_bf16.h>
#include <math.h>

#define L 128
#define B 4
#define H 768
#define LN_EPS 1e-5f
#define XROWS 272            // [p1:0..127 | p2:128..255 | pg:256 | ones:257 | 0:258..271]
#define DSTRIDE 73984        // 272*272

typedef __attribute__((ext_vector_type(8))) short short8;
typedef __attribute__((ext_vector_type(4))) float f32x4;
typedef __attribute__((ext_vector_type(16))) float f32x16;

static __device__ __forceinline__ unsigned f2bfu(float f) {
    unsigned u = __float_as_uint(f);
    return (u + 0x7FFFu + ((u >> 16) & 1u)) >> 16;
}
static __device__ __forceinline__ uint2 pk4(float4 v) {
    uint2 o;
    o.x = f2bfu(v.x) | (f2bfu(v.y) << 16);
    o.y = f2bfu(v.z) | (f2bfu(v.w) << 16);
    return o;
}
static __device__ __forceinline__ unsigned short f2b(float f) {
    union { __hip_bfloat16 h; unsigned short u; } cv;
    cv.h = __float2bfloat16(f);
    return cv.u;
}
static __device__ __forceinline__ float4 unpk4(uint2 p) {
    return make_float4(__uint_as_float(p.x << 16),
                       __uint_as_float(p.x & 0xffff0000u),
                       __uint_as_float(p.y << 16),
                       __uint_as_float(p.y & 0xffff0000u));
}
static __device__ __forceinline__ unsigned fkey(float x) {
    unsigned u = __float_as_uint(x);
    return (u >> 31) ? ~u : (u | 0x80000000u);
}

// ---------------------------------------------------------------------------
// kConv: all fp32->bf16 packing, coalesced READS + scattered 16B writes.
//  S1 apack [32mt][48ks][64lane][8]  S2 wpackA [48nt][48ks][64][8]
//  S3 wpackB [96nt][24ks][64][8]     S4 rwb2 [48 s][64 lane][8] (32x32x16 B-frag)
//  S5 X rows 257..271 (ones/zeros)   S6 gmax=0
// ---------------------------------------------------------------------------
__global__ __launch_bounds__(256) void kConv(const float* __restrict__ h_re,
                                             const float* __restrict__ h_share,
                                             const float* __restrict__ r_w,
                                             const float* __restrict__ hid_w,
                                             const float* __restrict__ rel_w,
                                             unsigned short* __restrict__ apack,
                                             unsigned short* __restrict__ wpackA,
                                             unsigned short* __restrict__ wpackB,
                                             unsigned short* __restrict__ rwb2,
                                             unsigned short* __restrict__ xb16,
                                             unsigned int* __restrict__ gmax) {
    int t = blockIdx.x * 256 + threadIdx.x;
    if (t >= 402816) return;
    if (t < 98304) {                          // apack: Acat=[h_share|h_re]
        int m = t / 192, oct = t % 192, k = oct * 8;
        const float* src = (k < 768) ? (h_share + (size_t)m * 768 + k)
                                     : (h_re + (size_t)m * 768 + k - 768);
        float4 x = *(const float4*)src, y = *(const float4*)(src + 4);
        int mt = m >> 4, lr = m & 15, ks = k >> 5, lq = (k >> 3) & 3;
        uint2* dst = (uint2*)(apack + (((size_t)mt * 48 + ks) * 64 + lq * 16 + lr) * 8);
        dst[0] = pk4(x); dst[1] = pk4(y);
    } else if (t < 245760) {                  // wpackA: r_w rows
        int t2 = t - 98304;
        int n = t2 / 192, oct = t2 % 192, k = oct * 8;
        const float* src = r_w + (size_t)n * 1536 + k;
        float4 x = *(const float4*)src, y = *(const float4*)(src + 4);
        int nt = n >> 4, lr = n & 15, ks = k >> 5, lq = (k >> 3) & 3;
        uint2* dst = (uint2*)(wpackA + (((size_t)nt * 48 + ks) * 64 + lq * 16 + lr) * 8);
        dst[0] = pk4(x); dst[1] = pk4(y);
    } else if (t < 393216) {                  // wpackB: hid_w rows (w1|w2)
        int t3 = t - 245760;
        int n = t3 / 96, oct = t3 % 96, k = oct * 8;
        int half = (n >= 768) ? 1 : 0;
        const float* src = hid_w + (size_t)(n - half * 768) * 2304 + half * 768 + k;
        float4 x = *(const float4*)src, y = *(const float4*)(src + 4);
        int nt = n >> 4, lr = n & 15, ks = k >> 5, lq = (k >> 3) & 3;
        uint2* dst = (uint2*)(wpackB + (((size_t)nt * 24 + ks) * 64 + lq * 16 + lr) * 8);
        dst[0] = pk4(x); dst[1] = pk4(y);
    } else if (t < 396288) {                  // rwb2: B-frag-linear rel_w (32x32x16)
        int t4 = t - 393216;                  // 0..3071: (s, lane)
        int s = t4 >> 6, l = t4 & 63;
        int row = l & 31;
        uint2 o0 = make_uint2(0u, 0u), o1 = o0;
        if (row < 24) {
            const float* src = rel_w + (size_t)row * 768 + s * 16 + (l >> 5) * 8;
            o0 = pk4(*(const float4*)src);
            o1 = pk4(*(const float4*)(src + 4));
        }
        uint2* dst = (uint2*)(rwb2 + (size_t)t4 * 8);
        dst[0] = o0; dst[1] = o1;
    } else if (t < 402048) {                  // X tail rows 257..271
        int t5 = t - 396288;
        int b = t5 / 1440, rem = t5 % 1440, row = 257 + rem / 96, oct = rem % 96;
        unsigned val = (row == 257) ? 0x3F803F80u : 0u;
        uint2* dst = (uint2*)(xb16 + ((size_t)b * XROWS + row) * 768 + oct * 8);
        dst[0] = make_uint2(val, val); dst[1] = make_uint2(val, val);
    } else {                                  // gmax zero (768 x uint4)
        int t6 = t - 402048;
        ((uint4*)gmax)[t6] = make_uint4(0u, 0u, 0u, 0u);
    }
}

// ---------------------------------------------------------------------------
// kGemm: 1-wave blocks, 32x32 per wave, packed coalesced operands.
//  blocks 0..383  (A): K=48 steps; in-reg + cross-lane max, then 1 atomic per
//                      (b,n) per lq==0 lane (8x fewer atomics than r8)
//  blocks 384..1151(B): K=24 steps, writes bf16 into X rows (p1/p2)
// ---------------------------------------------------------------------------
template<int KS>
static __device__ __forceinline__ void gemm_tile(const unsigned short* __restrict__ ap,
                                                 const unsigned short* __restrict__ wr,
                                                 f32x4 acc[2][2]) {
#pragma unroll 8
    for (int s = 0; s < KS; s++) {
        short8 a0 = *(const short8*)(ap + (size_t)s * 512);
        short8 a1 = *(const short8*)(ap + (size_t)(48 + s) * 512);
        short8 w0 = *(const short8*)(wr + (size_t)s * 512);
        short8 w1 = *(const short8*)(wr + (size_t)(KS + s) * 512);
        acc[0][0] = __builtin_amdgcn_mfma_f32_16x16x32_bf16(a0, w0, acc[0][0], 0, 0, 0);
        acc[0][1] = __builtin_amdgcn_mfma_f32_16x16x32_bf16(a0, w1, acc[0][1], 0, 0, 0);
        acc[1][0] = __builtin_amdgcn_mfma_f32_16x16x32_bf16(a1, w0, acc[1][0], 0, 0, 0);
        acc[1][1] = __builtin_amdgcn_mfma_f32_16x16x32_bf16(a1, w1, acc[1][1], 0, 0, 0);
    }
}

__global__ __launch_bounds__(64) void kGemm(const unsigned short* __restrict__ apack,
                                            const unsigned short* __restrict__ wpackA,
                                            const unsigned short* __restrict__ wpackB,
                                            unsigned int* __restrict__ gmax,
                                            unsigned short* __restrict__ xb16) {
    int id = blockIdx.x;
    int lane = threadIdx.x;
    int lq = lane >> 4, lr = lane & 15;
    f32x4 acc[2][2] = {{{0.f,0.f,0.f,0.f},{0.f,0.f,0.f,0.f}},
                       {{0.f,0.f,0.f,0.f},{0.f,0.f,0.f,0.f}}};
    if (id < 384) {
        int mt0 = (id / 24) * 2, nt0 = (id % 24) * 2;
        const unsigned short* ap = apack + (size_t)mt0 * 48 * 512 + lane * 8;
        const unsigned short* wr = wpackA + (size_t)nt0 * 48 * 512 + lane * 8;
        gemm_tile<48>(ap, wr, acc);
        // m = (mt0+mi)*16 + lq*4 + q  ->  b = q, l = 4*(mt0+mi) + lq.
        // For fixed (ni,q): 8 l-values live in {mi} x {lq lanes} -> pre-max all.
#pragma unroll
        for (int ni = 0; ni < 2; ni++)
#pragma unroll
            for (int q = 0; q < 4; q++) {
                float mx = fmaxf(acc[0][ni][q], acc[1][ni][q]);
                mx = fmaxf(mx, __shfl_xor(mx, 16, 64));
                mx = fmaxf(mx, __shfl_xor(mx, 32, 64));
                if (lq == 0) {
                    int n = (nt0 + ni) * 16 + lr;
                    atomicMax(&gmax[q * 768 + n], fkey(mx));
                }
            }
    } else {
        int id2 = id - 384;
        int mt0 = (id2 / 48) * 2, nt0 = (id2 % 48) * 2;
        const unsigned short* ap = apack + ((size_t)mt0 * 48 + 24) * 512 + lane * 8;
        const unsigned short* wr = wpackB + (size_t)nt0 * 24 * 512 + lane * 8;
        gemm_tile<24>(ap, wr, acc);
#pragma unroll
        for (int mi = 0; mi < 2; mi++)
#pragma unroll
            for (int ni = 0; ni < 2; ni++)
#pragma unroll
                for (int q = 0; q < 4; q++) {
                    int m = (mt0 + mi) * 16 + lq * 4 + q;
                    int n = (nt0 + ni) * 16 + lr;
                    int b = m & 3, l = m >> 2;
                    size_t row = (n < 768) ? (size_t)l : (size_t)(128 + l);
                    int col = (n < 768) ? n : n - 768;
                    xb16[((size_t)b * XROWS + row) * 768 + col] = f2b(acc[mi][ni][q]);
                }
    }
}

// ---------------------------------------------------------------------------
// kPg: decode gmax -> g = tanh(max+r_b), pg = g.w3 + hid_b -> X row 256 (bf16)
// ---------------------------------------------------------------------------
__global__ __launch_bounds__(256) void kPg(const unsigned int* __restrict__ gmax,
                                           const float* __restrict__ r_b,
                                           const float* __restrict__ hid_w,
                                           const float* __restrict__ hid_b,
                                           unsigned short* __restrict__ xb16) {
    __shared__ float sg[768];
    __shared__ float sp[4][64];
    int kt = blockIdx.x, b = blockIdx.y, tid = threadIdx.x;
    for (int v = tid; v < 768; v += 256) {
        unsigned key = gmax[b * 768 + v];
        unsigned bits = (key & 0x80000000u) ? (key & 0x7FFFFFFFu) : ~key;
        sg[v] = tanhf(__uint_as_float(bits) + r_b[v]);
    }
    __syncthreads();
    int kk = tid & 63, hc = tid >> 6;
    int k = kt * 64 + kk;
    const float4* w4 = (const float4*)hid_w;
    const float4* g4 = (const float4*)sg;
    float acc = 0.f;
    for (int h = hc * 48; h < hc * 48 + 48; h++) {
        float4 gv = g4[h];
        float4 wv = w4[(size_t)k * 576 + 384 + h];
        acc += gv.x * wv.x + gv.y * wv.y + gv.z * wv.z + gv.w * wv.w;
    }
    sp[hc][kk] = acc;
    __syncthreads();
    if (hc == 0) {
        float pgv = sp[0][kk] + sp[1][kk] + sp[2][kk] + sp[3][kk] + hid_b[k];
        xb16[((size_t)b * XROWS + 256) * 768 + k] = f2b(pgv);
    }
}

// ---------------------------------------------------------------------------
// kGram: D[b] = X[b] . X[b]^T  (272x272, K=768) via MFMA. grid (17,17,4), 64 thr.
// ---------------------------------------------------------------------------
__global__ __launch_bounds__(64) void kGram(const unsigned short* __restrict__ xb16,
                                            float* __restrict__ D) {
    int it = blockIdx.x, jt = blockIdx.y, b = blockIdx.z;
    int lane = threadIdx.x, lq = lane >> 4, lr = lane & 15;
    const unsigned short* ar = xb16 + ((size_t)b * XROWS + it * 16 + lr) * 768 + lq * 8;
    const unsigned short* wr = xb16 + ((size_t)b * XROWS + jt * 16 + lr) * 768 + lq * 8;
    f32x4 acc = {0.f, 0.f, 0.f, 0.f};
#pragma unroll 8
    for (int s = 0; s < 24; s++) {
        short8 a = *(const short8*)(ar + s * 32);
        short8 w = *(const short8*)(wr + s * 32);
        acc = __builtin_amdgcn_mfma_f32_16x16x32_bf16(a, w, acc, 0, 0, 0);
    }
    float* Db = D + (size_t)b * DSTRIDE;
#pragma unroll
    for (int q = 0; q < 4; q++)
        Db[(size_t)(it * 16 + lq * 4 + q) * XROWS + jt * 16 + lr] = acc[q];
}

// ---------------------------------------------------------------------------
// kC: block (i, b, jg) -> 32 j's, 512 thr (8 waves).
// Phase1: LN+ELU (stats from D) -> zls bf16 [32][780] (pad: stride 6 mod 32 banks).
// Phase2: one 32x32x16 MFMA chain per wave, K split 8 ways (6 steps each),
//         coalesced B-frags from rwb2, f32 partial reduce in aliased LDS.
// ---------------------------------------------------------------------------
__global__ __launch_bounds__(512, 6) void kC(const unsigned short* __restrict__ xb16,
                                             const float* __restrict__ ln_g,
                                             const float* __restrict__ ln_b,
                                             const unsigned short* __restrict__ rwb2,
                                             const float* __restrict__ rel_b,
                                             const float* __restrict__ D,
                                             const float* __restrict__ mask,
                                             float* __restrict__ out) {
    __shared__ __align__(16) unsigned char smem[49920];   // 32*780*2
    __shared__ float smu[32], srs[32];
    unsigned short (*zls)[780] = (unsigned short (*)[780])smem;
    int i = blockIdx.x, b = blockIdx.y, j0 = blockIdx.z * 32;
    int tid = threadIdx.x, lane = tid & 63, wave = tid >> 6;

    if (tid < 32) {
        const float* Db = D + (size_t)b * DSTRIDE;
        int vr = 128 + j0 + tid;
        float Su1 = Db[(size_t)i * XROWS + 257];
        float Su2 = Db[(size_t)i * XROWS + i];
        float up  = Db[(size_t)i * XROWS + 256];
        float Sp1 = Db[(size_t)256 * XROWS + 257];
        float Sp2 = Db[(size_t)256 * XROWS + 256];
        float Sv1 = Db[(size_t)vr * XROWS + 257];
        float Sv2 = Db[(size_t)vr * XROWS + vr];
        float Dij = Db[(size_t)i * XROWS + vr];
        float cvj = Db[(size_t)vr * XROWS + 256];
        float s1 = Su1 + Sp1 + Sv1;
        float s2 = Su2 + Sp2 + Sv2 + 2.f * (Dij + up + cvj);
        float mu = s1 * (1.f / 768.f);
        smu[tid] = mu;
        srs[tid] = rsqrtf(s2 * (1.f / 768.f) - mu * mu + LN_EPS);
    }
    const uint2* ur = (const uint2*)(xb16 + ((size_t)b * XROWS + i) * 768);
    const uint2* pr = (const uint2*)(xb16 + ((size_t)b * XROWS + 256) * 768);
    const float4* lg4 = (const float4*)ln_g;
    const float4* lb4 = (const float4*)ln_b;
    float4 t1[3], gg[3], bb[3];
#pragma unroll
    for (int s = 0; s < 3; s++) {
        int c = lane + 64 * s;
        float4 x = unpk4(ur[c]), y = unpk4(pr[c]);
        t1[s] = make_float4(x.x + y.x, x.y + y.y, x.z + y.z, x.w + y.w);
        gg[s] = lg4[c];
        bb[s] = lb4[c];
    }
    __syncthreads();

#pragma unroll
    for (int jj = 0; jj < 4; jj++) {
        int j = wave * 4 + jj;
        float mu = smu[j], rs = srs[j];
        const uint2* vr2 = (const uint2*)(xb16 + ((size_t)b * XROWS + 128 + j0 + j) * 768);
        uint2* zrow = (uint2*)&zls[j][0];
#pragma unroll
        for (int s = 0; s < 3; s++) {
            int c = lane + 64 * s;
            float4 vv = unpk4(vr2[c]);
            float A0 = rs * gg[s].x, A1 = rs * gg[s].y, A2 = rs * gg[s].z, A3 = rs * gg[s].w;
            float C0 = fmaf(-mu, A0, bb[s].x), C1 = fmaf(-mu, A1, bb[s].y);
            float C2 = fmaf(-mu, A2, bb[s].z), C3 = fmaf(-mu, A3, bb[s].w);
            float z0 = fmaf(t1[s].x + vv.x, A0, C0);
            float z1 = fmaf(t1[s].y + vv.y, A1, C1);
            float z2 = fmaf(t1[s].z + vv.z, A2, C2);
            float z3 = fmaf(t1[s].w + vv.w, A3, C3);
            z0 = fmaxf(z0, __expf(fminf(z0, 0.f)) - 1.f);
            z1 = fmaxf(z1, __expf(fminf(z1, 0.f)) - 1.f);
            z2 = fmaxf(z2, __expf(fminf(z2, 0.f)) - 1.f);
            z3 = fmaxf(z3, __expf(fminf(z3, 0.f)) - 1.f);
            uint2 o;
            o.x = (unsigned)f2b(z0) | ((unsigned)f2b(z1) << 16);
            o.y = (unsigned)f2b(z2) | ((unsigned)f2b(z3) << 16);
            zrow[c] = o;
        }
    }
    __syncthreads();

    // phase 2: wave kq handles K-steps kq*6..kq*6+5 of 48 (K=768, 16 per step)
    int arow = lane & 31, ahi = lane >> 5;
    f32x16 acc = {0.f,0.f,0.f,0.f, 0.f,0.f,0.f,0.f, 0.f,0.f,0.f,0.f, 0.f,0.f,0.f,0.f};
    const unsigned short* bptr = rwb2 + ((size_t)(wave * 6) * 64 + lane) * 8;
#pragma unroll
    for (int st = 0; st < 6; st++) {
        int s = wave * 6 + st;
        short8 a  = *(const short8*)&zls[arow][s * 16 + ahi * 8];
        short8 bf = *(const short8*)(bptr + (size_t)st * 512);
        acc = __builtin_amdgcn_mfma_f32_32x32x16_bf16(a, bf, acc, 0, 0, 0);
    }
    __syncthreads();
    float* pf = (float*)smem;                 // 8 waves x 1024 f32 = 32 KB
#pragma unroll
    for (int r = 0; r < 16; r++) {
        int row = (r & 3) + 8 * (r >> 2) + 4 * ahi;
        pf[wave * 1024 + row * 32 + arow] = acc[r];
    }
    __syncthreads();

#pragma unroll
    for (int e0 = 0; e0 < 2; e0++) {
        int e = tid + e0 * 512;
        int row = e >> 5, col = e & 31;
        if (col < 24) {
            float v = 0.f;
#pragma unroll
            for (int w = 0; w < 8; w++) v += pf[w * 1024 + e];
            int jgl = j0 + row;
            float mval = mask[i * 4 + b] * mask[jgl * 4 + b];
            out[((size_t)(i * 128 + jgl) * 4 + b) * 24 + col] =
                mval / (1.f + __expf(-(v + rel_b[col])));
        }
    }
}

// ---------------------------------------------------------------------------
extern "C" void kernel_launch(void* const* d_in, const int* in_sizes, int n_in,
                              void* d_out, int out_size, void* d_ws, size_t ws_size,
                              hipStream_t stream) {
    const float* h_re    = (const float*)d_in[0];
    const float* h_share = (const float*)d_in[1];
    const float* mask    = (const float*)d_in[2];
    const float* r_w     = (const float*)d_in[3];
    const float* r_b     = (const float*)d_in[4];
    const float* hid_w   = (const float*)d_in[5];
    const float* hid_b   = (const float*)d_in[6];
    const float* ln_g    = (const float*)d_in[7];
    const float* ln_b    = (const float*)d_in[8];
    const float* rel_w   = (const float*)d_in[9];
    const float* rel_b   = (const float*)d_in[10];
    float* out = (float*)d_out;

    float* ws = (float*)d_ws;
    unsigned short* apack  = (unsigned short*)(ws);             // 393216 f
    unsigned short* wpackA = (unsigned short*)(ws + 393216);    // 589824 f
    unsigned short* wpackB = (unsigned short*)(ws + 983040);    // 589824 f
    unsigned short* xb16   = (unsigned short*)(ws + 1572864);   // 417792 f
    float*          D      = ws + 1990656;                      // 295936 f
    unsigned int*   gmax   = (unsigned int*)(ws + 2286592);     // 3072
    unsigned short* rwb2   = (unsigned short*)(ws + 2289664);   // 12288 f

    kConv<<<1574, 256, 0, stream>>>(h_re, h_share, r_w, hid_w, rel_w,
                                    apack, wpackA, wpackB, rwb2, xb16, gmax);
    kGemm<<<1152, 64, 0, stream>>>(apack, wpackA, wpackB, gmax, xb16);
    kPg<<<dim3(12, 4), 256, 0, stream>>>(gmax, r_b, hid_w, hid_b, xb16);
    kGram<<<dim3(17, 17, 4), 64, 0, stream>>>(xb16, D);
    kC<<<dim3(L, B, 4), 512, 0, stream>>>(xb16, ln_g, ln_b, rwb2, rel_b,
                                          D, mask, out);
}